// Round 2
// baseline (3725.127 us; speedup 1.0000x reference)
//
#include <hip/hip_runtime.h>
#include <math.h>

#define N_NODES 50000
#define N_EDG   800000
#define ET      (N_EDG + N_NODES)   // +self loops
#define NH      8
#define DH      32
#define HID     256

// ---------------- fp32 tiled GEMM: C[M,NC] = act(A[M,K(lda)] @ W[K,NC] + bias)
// 64x64 tile, 256 threads, thread = 4 rows x 4 cols. ACT: 0 none, 1 tanh, 2 relu
template<int NC, int ACT>
__global__ __launch_bounds__(256)
void gemm_k(const float* __restrict__ A, int lda, const float* __restrict__ W,
            const float* __restrict__ bias, float* __restrict__ C,
            int M, int K) {
    __shared__ float As[64][68];   // [row][k], +4 pad (row stride 272B, 16B-mult)
    __shared__ float Ws[64][64];   // [k][col]
    const int tid = threadIdx.x;
    const int tx = tid & 15;       // col group
    const int ty = tid >> 4;       // row group
    const int r0 = blockIdx.x * 64;
    const int c0 = blockIdx.y * 64;
    float4 acc0 = make_float4(0.f,0.f,0.f,0.f);
    float4 acc1 = acc0, acc2 = acc0, acc3 = acc0;

    for (int k0 = 0; k0 < K; k0 += 64) {
        #pragma unroll
        for (int i = 0; i < 4; ++i) {
            int j  = tid + i * 256;          // 0..1023 float4 slots
            int r  = j >> 4;                 // 0..63
            int kk = (j & 15) << 2;          // 0..60
            int gr = r0 + r; if (gr >= M) gr = M - 1;   // clamp (stores guarded)
            *(float4*)&As[r][kk] = *(const float4*)&A[(size_t)gr * lda + k0 + kk];
            *(float4*)&Ws[r][kk] = *(const float4*)&W[(size_t)(k0 + r) * NC + c0 + kk];
        }
        __syncthreads();
        #pragma unroll
        for (int kk = 0; kk < 64; kk += 4) {
            float4 a0 = *(const float4*)&As[ty*4+0][kk];
            float4 a1 = *(const float4*)&As[ty*4+1][kk];
            float4 a2 = *(const float4*)&As[ty*4+2][kk];
            float4 a3 = *(const float4*)&As[ty*4+3][kk];
            float4 b0 = *(const float4*)&Ws[kk+0][tx*4];
            float4 b1 = *(const float4*)&Ws[kk+1][tx*4];
            float4 b2 = *(const float4*)&Ws[kk+2][tx*4];
            float4 b3 = *(const float4*)&Ws[kk+3][tx*4];
            #define FMA_ROW(AR, ACC)                                        \
                ACC.x += AR.x*b0.x + AR.y*b1.x + AR.z*b2.x + AR.w*b3.x;     \
                ACC.y += AR.x*b0.y + AR.y*b1.y + AR.z*b2.y + AR.w*b3.y;     \
                ACC.z += AR.x*b0.z + AR.y*b1.z + AR.z*b2.z + AR.w*b3.z;     \
                ACC.w += AR.x*b0.w + AR.y*b1.w + AR.z*b2.w + AR.w*b3.w;
            FMA_ROW(a0, acc0) FMA_ROW(a1, acc1) FMA_ROW(a2, acc2) FMA_ROW(a3, acc3)
            #undef FMA_ROW
        }
        __syncthreads();
    }
    float4 accs[4] = {acc0, acc1, acc2, acc3};
    #pragma unroll
    for (int r = 0; r < 4; ++r) {
        int gr = r0 + ty*4 + r;
        if (gr < M) {
            float4 v = accs[r];
            if (bias) {
                float4 bb = *(const float4*)&bias[c0 + tx*4];
                v.x += bb.x; v.y += bb.y; v.z += bb.z; v.w += bb.w;
            }
            if (ACT == 1) { v.x = tanhf(v.x); v.y = tanhf(v.y); v.z = tanhf(v.z); v.w = tanhf(v.w); }
            else if (ACT == 2) { v.x = fmaxf(v.x,0.f); v.y = fmaxf(v.y,0.f); v.z = fmaxf(v.z,0.f); v.w = fmaxf(v.w,0.f); }
            *(float4*)&C[(size_t)gr * NC + c0 + tx*4] = v;
        }
    }
}

// ---------------- per-(node,head) attention logits -------------------------
__global__ __launch_bounds__(256)
void attn_scores_k(const float* __restrict__ hp, const float* __restrict__ a_src,
                   const float* __restrict__ a_dst,
                   float* __restrict__ s_src, float* __restrict__ s_dst) {
    int gid = blockIdx.x * 256 + threadIdx.x;     // (n,h)
    if (gid >= N_NODES * NH) return;
    int h = gid & 7;
    const float4* hv = (const float4*)(hp + (size_t)gid * DH);  // n*256+h*32 == gid*32
    const float4* av = (const float4*)(a_src + h * DH);
    const float4* dv = (const float4*)(a_dst + h * DH);
    float ss = 0.f, sd = 0.f;
    #pragma unroll
    for (int i = 0; i < 8; ++i) {
        float4 x = hv[i], a = av[i], d = dv[i];
        ss += x.x*a.x + x.y*a.y + x.z*a.z + x.w*a.w;
        sd += x.x*d.x + x.y*d.y + x.z*d.z + x.w*d.w;
    }
    s_src[gid] = ss; s_dst[gid] = sd;
}

// ---------------- CSR build -------------------------------------------------
__global__ __launch_bounds__(256)
void zero_k(int* p, int n) { int i = blockIdx.x*256 + threadIdx.x; if (i < n) p[i] = 0; }

__global__ __launch_bounds__(256)
void count_k(const int* __restrict__ dst, int* __restrict__ counts) {
    int e = blockIdx.x*256 + threadIdx.x;
    if (e >= ET) return;
    int d = (e < N_EDG) ? dst[e] : (e - N_EDG);
    d = min(max(d, 0), N_NODES - 1);              // defensive clamp
    atomicAdd(&counts[d], 1);
}

__global__ __launch_bounds__(1024)
void scan_k(const int* counts, int* rowptr, int* fillptr, int n) {
    __shared__ int buf[1024];
    int tid = threadIdx.x;
    int carry = 0;
    for (int base = 0; base < n; base += 1024) {
        int i = base + tid;
        int v = (i < n) ? counts[i] : 0;
        buf[tid] = v;
        __syncthreads();
        for (int off = 1; off < 1024; off <<= 1) {
            int t = (tid >= off) ? buf[tid - off] : 0;
            __syncthreads();
            buf[tid] += t;
            __syncthreads();
        }
        int incl  = buf[tid];
        int total = buf[1023];
        int excl  = carry + incl - v;
        if (i < n) { rowptr[i] = excl; fillptr[i] = excl; }
        carry += total;
        __syncthreads();
    }
    if (tid == 0) rowptr[n] = carry;
}

__global__ __launch_bounds__(256)
void fill_k(const int* __restrict__ src, const int* __restrict__ dst,
            int* __restrict__ fillptr, int* __restrict__ srcs) {
    int e = blockIdx.x*256 + threadIdx.x;
    if (e >= ET) return;
    int s, d;
    if (e < N_EDG) { s = src[e]; d = dst[e]; } else { s = e - N_EDG; d = s; }
    s = min(max(s, 0), N_NODES - 1);              // defensive clamp
    d = min(max(d, 0), N_NODES - 1);
    int pos = atomicAdd(&fillptr[d], 1);
    pos = min(max(pos, 0), ET - 1);               // defensive clamp
    srcs[pos] = s;
}

// ---------------- segment-softmax aggregation: one wave per dst node --------
__global__ __launch_bounds__(256)
void agg_k(const int* __restrict__ rowptr, const int* __restrict__ srcs,
           const float* __restrict__ s_src, const float* __restrict__ s_dst,
           const float* __restrict__ hp, const float* __restrict__ bias,
           float* __restrict__ out, int out_stride, int out_off) {
    int wid  = (blockIdx.x * blockDim.x + threadIdx.x) >> 6;
    int lane = threadIdx.x & 63;
    if (wid >= N_NODES) return;
    const int n = wid;
    int r0 = rowptr[n], r1 = rowptr[n + 1];
    r0 = min(max(r0, 0), ET); r1 = min(max(r1, r0), ET);   // defensive clamp

    // pass 1: per-head max.  lane = slot*8 + h  (8 edge-slots x 8 heads)
    const int h1 = lane & 7, slot = lane >> 3;
    const float sd1 = s_dst[n*NH + h1];
    float mx = -1e30f;
    for (int i = r0 + slot; i < r1; i += 8) {
        int s = srcs[i];
        float ev = s_src[s*NH + h1] + sd1;
        ev = ev > 0.f ? ev : 0.2f * ev;
        mx = fmaxf(mx, ev);
    }
    mx = fmaxf(mx, __shfl_xor(mx, 8));
    mx = fmaxf(mx, __shfl_xor(mx, 16));
    mx = fmaxf(mx, __shfl_xor(mx, 32));
    // pass 1b: denominator
    float dn = 0.f;
    for (int i = r0 + slot; i < r1; i += 8) {
        int s = srcs[i];
        float ev = s_src[s*NH + h1] + sd1;
        ev = ev > 0.f ? ev : 0.2f * ev;
        dn += __expf(ev - mx);
    }
    dn += __shfl_xor(dn, 8);
    dn += __shfl_xor(dn, 16);
    dn += __shfl_xor(dn, 32);

    // pass 2: weighted sum. lane owns head h2=lane>>3, dims 4*(lane&7)..+3
    const int h2 = lane >> 3;
    const float m2  = __shfl(mx, h2);
    const float rdn = 1.f / __shfl(dn, h2);
    const float sd2 = __shfl(sd1, h2);
    float4 acc = make_float4(0.f,0.f,0.f,0.f);
    for (int i = r0; i < r1; ++i) {
        int s = srcs[i];
        float ev = s_src[s*NH + h2] + sd2;
        ev = ev > 0.f ? ev : 0.2f * ev;
        float w = __expf(ev - m2) * rdn;
        float4 v = *(const float4*)&hp[(size_t)s * HID + lane * 4];  // coalesced row
        acc.x += w*v.x; acc.y += w*v.y; acc.z += w*v.z; acc.w += w*v.w;
    }
    float4 bb = *(const float4*)&bias[lane * 4];
    acc.x += bb.x; acc.y += bb.y; acc.z += bb.z; acc.w += bb.w;
    acc.x = acc.x > 0.f ? acc.x : expm1f(acc.x);   // ELU
    acc.y = acc.y > 0.f ? acc.y : expm1f(acc.y);
    acc.z = acc.z > 0.f ? acc.z : expm1f(acc.z);
    acc.w = acc.w > 0.f ? acc.w : expm1f(acc.w);
    *(float4*)&out[(size_t)n * out_stride + out_off + lane * 4] = acc;
}

// ---------------- semantic attention: scores -> softmax -> z ----------------
// t: [N,3,128] tanh-projected. z written INTERLEAVED into t's arena at stride
// zstride (=384): wave n reads only its own rows, then overwrites them. Safe.
__global__ __launch_bounds__(256)
void score_z_k(const float* __restrict__ t, const float* __restrict__ W2,
               const float* __restrict__ emb, float* __restrict__ z, int zstride) {
    int wid  = (blockIdx.x * blockDim.x + threadIdx.x) >> 6;
    int lane = threadIdx.x & 63;
    if (wid >= N_NODES) return;
    const int n = wid;
    float sc[3];
    #pragma unroll
    for (int p = 0; p < 3; ++p) {
        const float* tr = t + (size_t)(n*3 + p) * 128;
        float part = tr[lane] * W2[lane] + tr[64 + lane] * W2[64 + lane];
        #pragma unroll
        for (int o = 1; o < 64; o <<= 1) part += __shfl_xor(part, o);
        sc[p] = part;
    }
    float m  = fmaxf(sc[0], fmaxf(sc[1], sc[2]));
    float e0 = __expf(sc[0]-m), e1 = __expf(sc[1]-m), e2 = __expf(sc[2]-m);
    float rs = 1.f / (e0 + e1 + e2);
    e0 *= rs; e1 *= rs; e2 *= rs;
    const float* er = emb + (size_t)n * 768;
    // read emb (separate buffer), write z into own rows of t-arena
    for (int c = lane; c < 256; c += 64)
        z[(size_t)n*zstride + c] = e0*er[c] + e1*er[256 + c] + e2*er[512 + c];
}

__global__ __launch_bounds__(256)
void logits_k(const float* __restrict__ hcls, const float* __restrict__ W2,
              const float* __restrict__ b2, float* __restrict__ out) {
    int gid = blockIdx.x*256 + threadIdx.x;
    if (gid >= N_NODES * 2) return;
    int n = gid >> 1, o = gid & 1;
    const float* hr = hcls + (size_t)n * 128;
    float a = b2[o];
    #pragma unroll 4
    for (int j = 0; j < 128; ++j) a += hr[j] * W2[j*2 + o];
    out[gid] = a;
}

// ---------------------------------------------------------------------------
extern "C" void kernel_launch(void* const* d_in, const int* in_sizes, int n_in,
                              void* d_out, int out_size, void* d_ws, size_t ws_size,
                              hipStream_t stream) {
    (void)in_sizes; (void)n_in; (void)out_size; (void)ws_size;
    const float* x     = (const float*)d_in[0];
    const int*   edges = (const int*)  d_in[1];
    const float* projW = (const float*)d_in[2];
    const float* projb = (const float*)d_in[3];
    const float* gatW  = (const float*)d_in[4];
    const float* gatAs = (const float*)d_in[5];
    const float* gatAd = (const float*)d_in[6];
    const float* gatB  = (const float*)d_in[7];
    const float* semW1 = (const float*)d_in[8];
    const float* semb1 = (const float*)d_in[9];
    const float* semW2 = (const float*)d_in[10];
    const float* clsW1 = (const float*)d_in[11];
    const float* clsb1 = (const float*)d_in[12];
    const float* clsW2 = (const float*)d_in[13];
    const float* clsb2 = (const float*)d_in[14];
    float* out = (float*)d_out;

    // workspace arena (floats). Total: 5*HF floats + ~7 MB small = ~251 MiB.
    float* arena = (float*)d_ws;
    const size_t HF = (size_t)N_NODES * HID;          // 12.8M floats
    float* h0   = arena;                              // [N,256]
    float* hp   = arena + HF;                         // [N,256] GEMM scratch
    float* emb  = arena + 2*HF;                       // [N,3,256]; slice p doubles
                                                      //  as layer-0 out (hbuf)
    float* ssrc = arena + 5*HF;                       // [N,8]
    float* sdst = ssrc + (size_t)N_NODES*NH;          // [N,8]
    int*   rowptr = (int*)(sdst + (size_t)N_NODES*NH);// [N+1]
    int*   fillp  = rowptr + (N_NODES + 2);           // counts/fill cursor
    int*   srcs   = fillp  + (N_NODES + 2);           // [ET]
    // final stage (h0, hp dead): tbuf [150000,128] over h0+hp; z interleaved
    // into tbuf at stride 384; hcls in the tail (ends exactly at 2*HF).
    float* tbuf = h0;                                 // 19.2M floats
    float* hcls = h0 + (size_t)150000 * 128;          // [N,128] -> ends at 2*HF

    dim3 blk(256);
    const int gN = (N_NODES + 63) / 64;               // 782 row tiles

    // h0 = x @ projW + projb
    gemm_k<256,0><<<dim3(gN,4), blk, 0, stream>>>(x, 128, projW, projb, h0, N_NODES, 128);

    for (int p = 0; p < 3; ++p) {
        const int* esrc = edges + (size_t)p * 2 * N_EDG;
        const int* edst = esrc + N_EDG;
        zero_k <<<(N_NODES+255)/256, blk, 0, stream>>>(fillp, N_NODES);
        count_k<<<(ET+255)/256,      blk, 0, stream>>>(edst, fillp);
        scan_k <<<1, 1024, 0, stream>>>(fillp, rowptr, fillp, N_NODES);
        fill_k <<<(ET+255)/256,      blk, 0, stream>>>(esrc, edst, fillp, srcs);

        float* embp = emb + (size_t)p * HID;          // slice p, row stride 768
        for (int l = 0; l < 2; ++l) {
            const int pl = p*2 + l;
            const float* W = gatW + (size_t)pl * HID * HID;
            const float* hin = (l == 0) ? h0 : embp;
            const int    hlda = (l == 0) ? HID : 3*HID;
            gemm_k<256,0><<<dim3(gN,4), blk, 0, stream>>>(hin, hlda, W, nullptr, hp, N_NODES, HID);
            attn_scores_k<<<(N_NODES*NH+255)/256, blk, 0, stream>>>(
                hp, gatAs + pl*HID, gatAd + pl*HID, ssrc, sdst);
            // both layers write into emb slice p (stride 768); layer 1
            // overwrites layer 0's values (only hp/scores are read). ELU fused.
            agg_k<<<(N_NODES*64)/256, blk, 0, stream>>>(
                rowptr, srcs, ssrc, sdst, hp, gatB + pl*HID, emb, 3*HID, p*HID);
        }
    }

    // semantic attention + classifier
    gemm_k<128,1><<<dim3((150000+63)/64, 2), blk, 0, stream>>>(emb, 256, semW1, semb1, tbuf, 150000, 256);
    score_z_k<<<(N_NODES*64)/256, blk, 0, stream>>>(tbuf, semW2, emb, tbuf, 384);
    gemm_k<128,2><<<dim3(gN, 2), blk, 0, stream>>>(tbuf, 384, clsW1, clsb1, hcls, N_NODES, 256);
    logits_k<<<(N_NODES*2+255)/256, blk, 0, stream>>>(hcls, clsW2, clsb2, out);
}

// Round 3
// 2168.343 us; speedup vs baseline: 1.7180x; 1.7180x over previous
//
#include <hip/hip_runtime.h>
#include <math.h>

#define N_NODES 50000
#define N_EDG   800000
#define ET      (N_EDG + N_NODES)   // +self loops
#define NH      8
#define DH      32
#define HID     256

typedef __attribute__((ext_vector_type(8))) short bf16x8;
typedef __attribute__((ext_vector_type(4))) float f32x4;

__device__ __forceinline__ unsigned short f2bf(float x) {
    unsigned u = __float_as_uint(x);
    u += 0x7FFF + ((u >> 16) & 1);          // RNE
    return (unsigned short)(u >> 16);
}
__device__ __forceinline__ float bf2f(unsigned short h) {
    return __uint_as_float(((unsigned)h) << 16);
}

// ---------------- bf16x3 MFMA GEMM --------------------------------------
// C[M,NC] = act(A @ W + bias), A given as hi/lo bf16 planes (row stride lda),
// W given as transposed hi/lo planes WT[NC][K]. 128x128 tile, 256 thr, BK=32.
// Per wave: 4x4 grid of 16x16x32 tiles; 3 MFMAs per tile (hi*hi+hi*lo+lo*hi).
// OUTPAIR=1: write hi/lo bf16 planes instead of f32.
#define SK 40   // padded LDS row stride (elems): 80 B -> ~2-way banks (free)
template<int NC, int ACT, int OUTPAIR>
__global__ __launch_bounds__(256)
void mfma_gemm_k(const unsigned short* __restrict__ Ahi,
                 const unsigned short* __restrict__ Alo, int lda,
                 const unsigned short* __restrict__ WThi,
                 const unsigned short* __restrict__ WTlo,
                 const float* __restrict__ bias,
                 float* __restrict__ C,
                 unsigned short* __restrict__ Chi, unsigned short* __restrict__ Clo,
                 int ldc, int M, int K) {
    __shared__ unsigned short sAh[128*SK], sAl[128*SK], sBh[128*SK], sBl[128*SK];
    const int tid  = threadIdx.x;
    const int lane = tid & 63;
    const int w    = tid >> 6;
    const int wr   = w >> 1, wc = w & 1;
    const int r0   = blockIdx.x * 128;
    const int c0   = blockIdx.y * 128;
    const int l15  = lane & 15, q = lane >> 4;

    f32x4 acc[4][4];
    #pragma unroll
    for (int i = 0; i < 4; ++i)
        #pragma unroll
        for (int j = 0; j < 4; ++j) acc[i][j] = (f32x4){0.f, 0.f, 0.f, 0.f};

    for (int kc = 0; kc < K; kc += 32) {
        // stage 4 planes: 128 rows x 32 elems each; thread does 2x16B per plane
        #pragma unroll
        for (int i = 0; i < 2; ++i) {
            int idx  = tid + i * 256;          // 0..511
            int row  = idx >> 2, slot = idx & 3;
            int ar   = min(r0 + row, M - 1);
            int ga   = ar * lda + kc + slot * 8;
            int gb   = (c0 + row) * K + kc + slot * 8;
            int ld   = row * SK + slot * 8;
            *(uint4*)&sAh[ld] = *(const uint4*)&Ahi[ga];
            *(uint4*)&sAl[ld] = *(const uint4*)&Alo[ga];
            *(uint4*)&sBh[ld] = *(const uint4*)&WThi[gb];
            *(uint4*)&sBl[ld] = *(const uint4*)&WTlo[gb];
        }
        __syncthreads();
        bf16x8 fAh[4], fAl[4], fBh[4], fBl[4];
        #pragma unroll
        for (int t = 0; t < 4; ++t) {
            int ra = (wr*64 + t*16 + l15) * SK + q*8;
            int rb = (wc*64 + t*16 + l15) * SK + q*8;
            fAh[t] = *(const bf16x8*)&sAh[ra];
            fAl[t] = *(const bf16x8*)&sAl[ra];
            fBh[t] = *(const bf16x8*)&sBh[rb];
            fBl[t] = *(const bf16x8*)&sBl[rb];
        }
        #pragma unroll
        for (int mt = 0; mt < 4; ++mt)
            #pragma unroll
            for (int nt = 0; nt < 4; ++nt) {
                acc[mt][nt] = __builtin_amdgcn_mfma_f32_16x16x32_bf16(fAh[mt], fBh[nt], acc[mt][nt], 0, 0, 0);
                acc[mt][nt] = __builtin_amdgcn_mfma_f32_16x16x32_bf16(fAh[mt], fBl[nt], acc[mt][nt], 0, 0, 0);
                acc[mt][nt] = __builtin_amdgcn_mfma_f32_16x16x32_bf16(fAl[mt], fBh[nt], acc[mt][nt], 0, 0, 0);
            }
        __syncthreads();
    }
    // epilogue: C/D layout col=lane&15, row=(lane>>4)*4+reg  [m89-verified]
    #pragma unroll
    for (int mt = 0; mt < 4; ++mt)
        #pragma unroll
        for (int nt = 0; nt < 4; ++nt) {
            int col = c0 + wc*64 + nt*16 + l15;
            float bb = bias ? bias[col] : 0.f;
            #pragma unroll
            for (int r = 0; r < 4; ++r) {
                int grow = r0 + wr*64 + mt*16 + q*4 + r;
                if (grow < M) {
                    float v = acc[mt][nt][r] + bb;
                    if (ACT == 1) v = tanhf(v);
                    else if (ACT == 2) v = fmaxf(v, 0.f);
                    size_t o = (size_t)grow * ldc + col;
                    if (OUTPAIR) {
                        unsigned short h = f2bf(v);
                        Chi[o] = h;
                        Clo[o] = f2bf(v - bf2f(h));
                    } else {
                        C[o] = v;
                    }
                }
            }
        }
}

// ---------------- conversions -------------------------------------------
// W[K][N] f32 -> WT hi/lo [N][K] bf16
__global__ __launch_bounds__(256)
void cvtW_k(const float* __restrict__ W, unsigned short* __restrict__ WThi,
            unsigned short* __restrict__ WTlo, int K, int N) {
    int idx = blockIdx.x * 256 + threadIdx.x;
    if (idx >= K * N) return;
    int k = idx / N, n = idx - k * N;
    float v = W[idx];
    unsigned short h = f2bf(v);
    WThi[n * K + k] = h;
    WTlo[n * K + k] = f2bf(v - bf2f(h));
}

// A[M][K] f32 (row stride lda) -> packed hi/lo [M][K] bf16
__global__ __launch_bounds__(256)
void cvtA_k(const float* __restrict__ A, int lda, int M, int K,
            unsigned short* __restrict__ hi, unsigned short* __restrict__ lo) {
    int idx = blockIdx.x * 256 + threadIdx.x;      // float4 units
    int kq = K >> 2;
    if (idx >= M * kq) return;
    int r = idx / kq, c = (idx - r * kq) * 4;
    float4 v = *(const float4*)&A[(size_t)r * lda + c];
    ushort4 h, l;
    h.x = f2bf(v.x); l.x = f2bf(v.x - bf2f(h.x));
    h.y = f2bf(v.y); l.y = f2bf(v.y - bf2f(h.y));
    h.z = f2bf(v.z); l.z = f2bf(v.z - bf2f(h.z));
    h.w = f2bf(v.w); l.w = f2bf(v.w - bf2f(h.w));
    *(ushort4*)&hi[(size_t)r * K + c] = h;
    *(ushort4*)&lo[(size_t)r * K + c] = l;
}

// ---------------- per-(node,head) attention logits -----------------------
__global__ __launch_bounds__(256)
void attn_scores_k(const float* __restrict__ hp, const float* __restrict__ a_src,
                   const float* __restrict__ a_dst,
                   float* __restrict__ s_src, float* __restrict__ s_dst) {
    int gid = blockIdx.x * 256 + threadIdx.x;     // (n,h)
    if (gid >= N_NODES * NH) return;
    int h = gid & 7;
    const float4* hv = (const float4*)(hp + (size_t)gid * DH);
    const float4* av = (const float4*)(a_src + h * DH);
    const float4* dv = (const float4*)(a_dst + h * DH);
    float ss = 0.f, sd = 0.f;
    #pragma unroll
    for (int i = 0; i < 8; ++i) {
        float4 x = hv[i], a = av[i], d = dv[i];
        ss += x.x*a.x + x.y*a.y + x.z*a.z + x.w*a.w;
        sd += x.x*d.x + x.y*d.y + x.z*d.z + x.w*d.w;
    }
    s_src[gid] = ss; s_dst[gid] = sd;
}

// ---------------- CSR build ----------------------------------------------
__global__ __launch_bounds__(256)
void zero_k(int* p, int n) { int i = blockIdx.x*256 + threadIdx.x; if (i < n) p[i] = 0; }

__global__ __launch_bounds__(256)
void count_k(const int* __restrict__ dst, int* __restrict__ counts) {
    int e = blockIdx.x*256 + threadIdx.x;
    if (e >= ET) return;
    int d = (e < N_EDG) ? dst[e] : (e - N_EDG);
    d = min(max(d, 0), N_NODES - 1);
    atomicAdd(&counts[d], 1);
}

__global__ __launch_bounds__(1024)
void scan_k(const int* counts, int* rowptr, int* fillptr, int n) {
    __shared__ int buf[1024];
    int tid = threadIdx.x;
    int carry = 0;
    for (int base = 0; base < n; base += 1024) {
        int i = base + tid;
        int v = (i < n) ? counts[i] : 0;
        buf[tid] = v;
        __syncthreads();
        for (int off = 1; off < 1024; off <<= 1) {
            int t = (tid >= off) ? buf[tid - off] : 0;
            __syncthreads();
            buf[tid] += t;
            __syncthreads();
        }
        int incl  = buf[tid];
        int total = buf[1023];
        int excl  = carry + incl - v;
        if (i < n) { rowptr[i] = excl; fillptr[i] = excl; }
        carry += total;
        __syncthreads();
    }
    if (tid == 0) rowptr[n] = carry;
}

__global__ __launch_bounds__(256)
void fill_k(const int* __restrict__ src, const int* __restrict__ dst,
            int* __restrict__ fillptr, int* __restrict__ srcs) {
    int e = blockIdx.x*256 + threadIdx.x;
    if (e >= ET) return;
    int s, d;
    if (e < N_EDG) { s = src[e]; d = dst[e]; } else { s = e - N_EDG; d = s; }
    s = min(max(s, 0), N_NODES - 1);
    d = min(max(d, 0), N_NODES - 1);
    int pos = atomicAdd(&fillptr[d], 1);
    pos = min(max(pos, 0), ET - 1);
    srcs[pos] = s;
}

// ---------------- segment-softmax aggregation: one wave per dst node -----
// epilogue: bias + ELU, then split to bf16 hi/lo planes (stride 768, off p*256)
__global__ __launch_bounds__(256)
void agg_k(const int* __restrict__ rowptr, const int* __restrict__ srcs,
           const float* __restrict__ s_src, const float* __restrict__ s_dst,
           const float* __restrict__ hp, const float* __restrict__ bias,
           unsigned short* __restrict__ outhi, unsigned short* __restrict__ outlo,
           int out_off) {
    int wid  = (blockIdx.x * blockDim.x + threadIdx.x) >> 6;
    int lane = threadIdx.x & 63;
    if (wid >= N_NODES) return;
    const int n = wid;
    int r0 = rowptr[n], r1 = rowptr[n + 1];
    r0 = min(max(r0, 0), ET); r1 = min(max(r1, r0), ET);

    const int h1 = lane & 7, slot = lane >> 3;
    const float sd1 = s_dst[n*NH + h1];
    float mx = -1e30f;
    for (int i = r0 + slot; i < r1; i += 8) {
        int s = srcs[i];
        float ev = s_src[s*NH + h1] + sd1;
        ev = ev > 0.f ? ev : 0.2f * ev;
        mx = fmaxf(mx, ev);
    }
    mx = fmaxf(mx, __shfl_xor(mx, 8));
    mx = fmaxf(mx, __shfl_xor(mx, 16));
    mx = fmaxf(mx, __shfl_xor(mx, 32));
    float dn = 0.f;
    for (int i = r0 + slot; i < r1; i += 8) {
        int s = srcs[i];
        float ev = s_src[s*NH + h1] + sd1;
        ev = ev > 0.f ? ev : 0.2f * ev;
        dn += __expf(ev - mx);
    }
    dn += __shfl_xor(dn, 8);
    dn += __shfl_xor(dn, 16);
    dn += __shfl_xor(dn, 32);

    const int h2 = lane >> 3;
    const float m2  = __shfl(mx, h2);
    const float rdn = 1.f / __shfl(dn, h2);
    const float sd2 = __shfl(sd1, h2);
    float4 acc = make_float4(0.f,0.f,0.f,0.f);
    for (int i = r0; i < r1; ++i) {
        int s = srcs[i];
        float ev = s_src[s*NH + h2] + sd2;
        ev = ev > 0.f ? ev : 0.2f * ev;
        float ww = __expf(ev - m2) * rdn;
        float4 v = *(const float4*)&hp[(size_t)s * HID + lane * 4];
        acc.x += ww*v.x; acc.y += ww*v.y; acc.z += ww*v.z; acc.w += ww*v.w;
    }
    float4 bb = *(const float4*)&bias[lane * 4];
    acc.x += bb.x; acc.y += bb.y; acc.z += bb.z; acc.w += bb.w;
    acc.x = acc.x > 0.f ? acc.x : expm1f(acc.x);   // ELU
    acc.y = acc.y > 0.f ? acc.y : expm1f(acc.y);
    acc.z = acc.z > 0.f ? acc.z : expm1f(acc.z);
    acc.w = acc.w > 0.f ? acc.w : expm1f(acc.w);
    ushort4 hh, ll;
    hh.x = f2bf(acc.x); ll.x = f2bf(acc.x - bf2f(hh.x));
    hh.y = f2bf(acc.y); ll.y = f2bf(acc.y - bf2f(hh.y));
    hh.z = f2bf(acc.z); ll.z = f2bf(acc.z - bf2f(hh.z));
    hh.w = f2bf(acc.w); ll.w = f2bf(acc.w - bf2f(hh.w));
    size_t o = (size_t)n * 768 + out_off + lane * 4;
    *(ushort4*)&outhi[o] = hh;
    *(ushort4*)&outlo[o] = ll;
}

// ---------------- semantic attention: scores -> softmax -> z -------------
// t [N,3,128] f32; emb given as hi/lo planes [N][768]; z written into t's
// arena at stride 384 (wave n touches only its own rows).
__global__ __launch_bounds__(256)
void score_z_k(const float* t, const float* __restrict__ W2,
               const unsigned short* __restrict__ ehi,
               const unsigned short* __restrict__ elo,
               float* z) {
    int wid  = (blockIdx.x * blockDim.x + threadIdx.x) >> 6;
    int lane = threadIdx.x & 63;
    if (wid >= N_NODES) return;
    const int n = wid;
    float sc[3];
    #pragma unroll
    for (int p = 0; p < 3; ++p) {
        const float* tr = t + (size_t)(n*3 + p) * 128;
        float part = tr[lane] * W2[lane] + tr[64 + lane] * W2[64 + lane];
        #pragma unroll
        for (int o = 1; o < 64; o <<= 1) part += __shfl_xor(part, o);
        sc[p] = part;
    }
    float m  = fmaxf(sc[0], fmaxf(sc[1], sc[2]));
    float e0 = __expf(sc[0]-m), e1 = __expf(sc[1]-m), e2 = __expf(sc[2]-m);
    float rs = 1.f / (e0 + e1 + e2);
    e0 *= rs; e1 *= rs; e2 *= rs;
    const unsigned short* rh = ehi + (size_t)n * 768;
    const unsigned short* rl = elo + (size_t)n * 768;
    for (int c = lane; c < 256; c += 64) {
        float v0 = bf2f(rh[c])       + bf2f(rl[c]);
        float v1 = bf2f(rh[256 + c]) + bf2f(rl[256 + c]);
        float v2 = bf2f(rh[512 + c]) + bf2f(rl[512 + c]);
        z[(size_t)n*384 + c] = e0*v0 + e1*v1 + e2*v2;
    }
}

__global__ __launch_bounds__(256)
void logits_k(const float* __restrict__ hcls, const float* __restrict__ W2,
              const float* __restrict__ b2, float* __restrict__ out) {
    int gid = blockIdx.x*256 + threadIdx.x;
    if (gid >= N_NODES * 2) return;
    int n = gid >> 1, o = gid & 1;
    const float* hr = hcls + (size_t)n * 128;
    float a = b2[o];
    #pragma unroll 4
    for (int j = 0; j < 128; ++j) a += hr[j] * W2[j*2 + o];
    out[gid] = a;
}

// -------------------------------------------------------------------------
extern "C" void kernel_launch(void* const* d_in, const int* in_sizes, int n_in,
                              void* d_out, int out_size, void* d_ws, size_t ws_size,
                              hipStream_t stream) {
    (void)in_sizes; (void)n_in; (void)out_size; (void)ws_size;
    const float* x     = (const float*)d_in[0];
    const int*   edges = (const int*)  d_in[1];
    const float* projW = (const float*)d_in[2];
    const float* projb = (const float*)d_in[3];
    const float* gatW  = (const float*)d_in[4];
    const float* gatAs = (const float*)d_in[5];
    const float* gatAd = (const float*)d_in[6];
    const float* gatB  = (const float*)d_in[7];
    const float* semW1 = (const float*)d_in[8];
    const float* semb1 = (const float*)d_in[9];
    const float* semW2 = (const float*)d_in[10];
    const float* clsW1 = (const float*)d_in[11];
    const float* clsb1 = (const float*)d_in[12];
    const float* clsW2 = (const float*)d_in[13];
    const float* clsb2 = (const float*)d_in[14];
    float* out = (float*)d_out;

    // ---- byte-addressed arena, total ~263.5 MB ----
    char* base = (char*)d_ws;
    const size_t MB = 1024*1024ull;
    const size_t PLANE = (size_t)N_NODES * HID * 2;      // 25.6 MB (bf16 plane)
    unsigned short* h0hi = (unsigned short*)(base);
    unsigned short* h0lo = (unsigned short*)(base + PLANE);
    float*          hp   = (float*)(base + 2*PLANE);                  // 51.2 MB
    unsigned short* ehi  = (unsigned short*)(base + 4*PLANE);         // 76.8 MB
    unsigned short* elo  = (unsigned short*)(base + 7*PLANE);         // 76.8 MB
    char* small = base + 10*PLANE;                                    // at 256 MB
    float* ssrc = (float*)small;
    float* sdst = ssrc + (size_t)N_NODES*NH;
    int*   rowptr = (int*)(sdst + (size_t)N_NODES*NH);
    int*   fillp  = rowptr + (N_NODES + 2);
    int*   srcs   = fillp  + (N_NODES + 2);
    unsigned short* WThi = (unsigned short*)(srcs + ET);   // 256x256 bf16
    unsigned short* WTlo = WThi + 65536;
    // overlays:
    unsigned short* xhi = ehi;                              // before emb writes
    unsigned short* xlo = ehi + (size_t)N_NODES * 128;
    float* tbuf = (float*)base;                             // [0,76.8M) over h0pair+hp
    float* hcls = (float*)(base + 3*PLANE);                 // [76.8,102.4M)
    unsigned short* zhi = (unsigned short*)(base + 4*PLANE);// over emb (dead)
    unsigned short* zlo = zhi + (size_t)N_NODES * HID;

    dim3 blk(256);
    const int gx  = (N_NODES + 127) / 128;    // 391

    // ---- projection: h0pair = split(x @ projW + projb) ----
    cvtA_k<<<(N_NODES*32 + 255)/256, blk, 0, stream>>>(x, 128, N_NODES, 128, xhi, xlo);
    cvtW_k<<<(128*256 + 255)/256, blk, 0, stream>>>(projW, WThi, WTlo, 128, 256);
    mfma_gemm_k<256,0,1><<<dim3(gx,2), blk, 0, stream>>>(
        xhi, xlo, 128, WThi, WTlo, projb, nullptr, h0hi, h0lo, 256, N_NODES, 128);

    for (int p = 0; p < 3; ++p) {
        const int* esrc = edges + (size_t)p * 2 * N_EDG;
        const int* edst = esrc + N_EDG;
        zero_k <<<(N_NODES+255)/256, blk, 0, stream>>>(fillp, N_NODES);
        count_k<<<(ET+255)/256,      blk, 0, stream>>>(edst, fillp);
        scan_k <<<1, 1024, 0, stream>>>(fillp, rowptr, fillp, N_NODES);
        fill_k <<<(ET+255)/256,      blk, 0, stream>>>(esrc, edst, fillp, srcs);

        for (int l = 0; l < 2; ++l) {
            const int pl = p*2 + l;
            cvtW_k<<<(256*256 + 255)/256, blk, 0, stream>>>(
                gatW + (size_t)pl * HID * HID, WThi, WTlo, 256, 256);
            const unsigned short* Ah = (l == 0) ? h0hi : ehi + p*HID;
            const unsigned short* Al = (l == 0) ? h0lo : elo + p*HID;
            const int lda = (l == 0) ? HID : 3*HID;
            mfma_gemm_k<256,0,0><<<dim3(gx,2), blk, 0, stream>>>(
                Ah, Al, lda, WThi, WTlo, nullptr, hp, nullptr, nullptr, HID, N_NODES, HID);
            attn_scores_k<<<(N_NODES*NH+255)/256, blk, 0, stream>>>(
                hp, gatAs + pl*HID, gatAd + pl*HID, ssrc, sdst);
            agg_k<<<(N_NODES*64)/256, blk, 0, stream>>>(
                rowptr, srcs, ssrc, sdst, hp, gatB + pl*HID, ehi, elo, p*HID);
        }
    }

    // ---- semantic attention + classifier ----
    cvtW_k<<<(256*128 + 255)/256, blk, 0, stream>>>(semW1, WThi, WTlo, 256, 128);
    mfma_gemm_k<128,1,0><<<dim3((150000+127)/128, 1), blk, 0, stream>>>(
        ehi, elo, 256, WThi, WTlo, semb1, tbuf, nullptr, nullptr, 128, 150000, 256);
    score_z_k<<<(N_NODES*64)/256, blk, 0, stream>>>(tbuf, semW2, ehi, elo, tbuf);
    cvtA_k<<<(N_NODES*64 + 255)/256, blk, 0, stream>>>(tbuf, 384, N_NODES, 256, zhi, zlo);
    cvtW_k<<<(256*128 + 255)/256, blk, 0, stream>>>(clsW1, WThi, WTlo, 256, 128);
    mfma_gemm_k<128,2,0><<<dim3(gx, 1), blk, 0, stream>>>(
        zhi, zlo, 256, WThi, WTlo, clsb1, hcls, nullptr, nullptr, 128, N_NODES, 256);
    logits_k<<<(N_NODES*2+255)/256, blk, 0, stream>>>(hcls, clsW2, clsb2, out);
    (void)MB;
}

// Round 4
// 1870.350 us; speedup vs baseline: 1.9917x; 1.1593x over previous
//
#include <hip/hip_runtime.h>
#include <math.h>

#define N_NODES 50000
#define N_EDG   800000
#define ET      (N_EDG + N_NODES)   // +self loops
#define NH      8
#define DH      32
#define HID     256

typedef __attribute__((ext_vector_type(8))) short bf16x8;
typedef __attribute__((ext_vector_type(4))) float f32x4;

__device__ __forceinline__ unsigned short f2bf(float x) {
    unsigned u = __float_as_uint(x);
    u += 0x7FFF + ((u >> 16) & 1);          // RNE
    return (unsigned short)(u >> 16);
}
__device__ __forceinline__ float bf2f(unsigned short h) {
    return __uint_as_float(((unsigned)h) << 16);
}

// ---------------- bf16x3 MFMA GEMM --------------------------------------
// C[M,NC] = act(A @ W + bias), A as hi/lo bf16 planes (row stride lda),
// W as transposed hi/lo planes WT[NC][K]. 128x128 tile, 256 thr, BK=32.
// Software-pipelined: step k+1's global loads issued before step k's MFMAs.
#define SK 40   // padded LDS row stride (elems): 80 B -> <=2-way banks (free)
template<int NC, int ACT, int OUTPAIR>
__global__ __launch_bounds__(256)
void mfma_gemm_k(const unsigned short* __restrict__ Ahi,
                 const unsigned short* __restrict__ Alo, int lda,
                 const unsigned short* __restrict__ WThi,
                 const unsigned short* __restrict__ WTlo,
                 const float* __restrict__ bias,
                 float* __restrict__ C,
                 unsigned short* __restrict__ Chi, unsigned short* __restrict__ Clo,
                 int ldc, int M, int K) {
    __shared__ unsigned short sAh[128*SK], sAl[128*SK], sBh[128*SK], sBl[128*SK];
    const int tid  = threadIdx.x;
    const int lane = tid & 63;
    const int w    = tid >> 6;
    const int wr   = w >> 1, wc = w & 1;
    const int r0   = blockIdx.x * 128;
    const int c0   = blockIdx.y * 128;
    const int l15  = lane & 15, q = lane >> 4;

    // staging addresses (fixed per thread): rows row0=tid>>2, row1=row0+64
    const int srow = tid >> 2, slot = tid & 3;
    const size_t gaB0 = (size_t)min(r0 + srow,      M - 1) * lda + slot * 8;
    const size_t gaB1 = (size_t)min(r0 + srow + 64, M - 1) * lda + slot * 8;
    const size_t gbB0 = (size_t)(c0 + srow)      * K + slot * 8;
    const size_t gbB1 = (size_t)(c0 + srow + 64) * K + slot * 8;
    const int    ld0  = srow * SK + slot * 8;
    const int    ld1  = (srow + 64) * SK + slot * 8;

    f32x4 acc[4][4];
    #pragma unroll
    for (int i = 0; i < 4; ++i)
        #pragma unroll
        for (int j = 0; j < 4; ++j) acc[i][j] = (f32x4){0.f, 0.f, 0.f, 0.f};

    uint4 rAh0, rAh1, rAl0, rAl1, rBh0, rBh1, rBl0, rBl1;
    #define GLB_LOAD(kc)                                            \
        rAh0 = *(const uint4*)&Ahi[gaB0 + (kc)];                    \
        rAh1 = *(const uint4*)&Ahi[gaB1 + (kc)];                    \
        rAl0 = *(const uint4*)&Alo[gaB0 + (kc)];                    \
        rAl1 = *(const uint4*)&Alo[gaB1 + (kc)];                    \
        rBh0 = *(const uint4*)&WThi[gbB0 + (kc)];                   \
        rBh1 = *(const uint4*)&WThi[gbB1 + (kc)];                   \
        rBl0 = *(const uint4*)&WTlo[gbB0 + (kc)];                   \
        rBl1 = *(const uint4*)&WTlo[gbB1 + (kc)];

    const int nsteps = K >> 5;
    GLB_LOAD(0)
    for (int s = 0; s < nsteps; ++s) {
        __syncthreads();                       // prior step's LDS reads done
        *(uint4*)&sAh[ld0] = rAh0; *(uint4*)&sAh[ld1] = rAh1;
        *(uint4*)&sAl[ld0] = rAl0; *(uint4*)&sAl[ld1] = rAl1;
        *(uint4*)&sBh[ld0] = rBh0; *(uint4*)&sBh[ld1] = rBh1;
        *(uint4*)&sBl[ld0] = rBl0; *(uint4*)&sBl[ld1] = rBl1;
        __syncthreads();
        if (s + 1 < nsteps) { GLB_LOAD((s + 1) << 5) }   // in flight during MFMA

        bf16x8 fAh[4], fAl[4];
        #pragma unroll
        for (int t = 0; t < 4; ++t) {
            int ra = (wr*64 + t*16 + l15) * SK + q*8;
            fAh[t] = *(const bf16x8*)&sAh[ra];
            fAl[t] = *(const bf16x8*)&sAl[ra];
        }
        #pragma unroll
        for (int nt = 0; nt < 4; ++nt) {
            int rb = (wc*64 + nt*16 + l15) * SK + q*8;
            bf16x8 fBh = *(const bf16x8*)&sBh[rb];
            bf16x8 fBl = *(const bf16x8*)&sBl[rb];
            #pragma unroll
            for (int mt = 0; mt < 4; ++mt) {
                acc[mt][nt] = __builtin_amdgcn_mfma_f32_16x16x32_bf16(fAh[mt], fBh, acc[mt][nt], 0, 0, 0);
                acc[mt][nt] = __builtin_amdgcn_mfma_f32_16x16x32_bf16(fAh[mt], fBl, acc[mt][nt], 0, 0, 0);
                acc[mt][nt] = __builtin_amdgcn_mfma_f32_16x16x32_bf16(fAl[mt], fBh, acc[mt][nt], 0, 0, 0);
            }
        }
    }
    #undef GLB_LOAD
    // epilogue: C/D layout col=lane&15, row=(lane>>4)*4+reg  [m89-verified]
    #pragma unroll
    for (int mt = 0; mt < 4; ++mt)
        #pragma unroll
        for (int nt = 0; nt < 4; ++nt) {
            int col = c0 + wc*64 + nt*16 + l15;
            float bb = bias ? bias[col] : 0.f;
            #pragma unroll
            for (int r = 0; r < 4; ++r) {
                int grow = r0 + wr*64 + mt*16 + q*4 + r;
                if (grow < M) {
                    float v = acc[mt][nt][r] + bb;
                    if (ACT == 1) v = tanhf(v);
                    else if (ACT == 2) v = fmaxf(v, 0.f);
                    size_t o = (size_t)grow * ldc + col;
                    if (OUTPAIR) {
                        unsigned short h = f2bf(v);
                        Chi[o] = h;
                        Clo[o] = f2bf(v - bf2f(h));
                    } else {
                        C[o] = v;
                    }
                }
            }
        }
}

// ---------------- conversions -------------------------------------------
__global__ __launch_bounds__(256)
void cvtW_k(const float* __restrict__ W, unsigned short* __restrict__ WThi,
            unsigned short* __restrict__ WTlo, int K, int N) {
    int idx = blockIdx.x * 256 + threadIdx.x;
    if (idx >= K * N) return;
    int k = idx / N, n = idx - k * N;
    float v = W[idx];
    unsigned short h = f2bf(v);
    WThi[n * K + k] = h;
    WTlo[n * K + k] = f2bf(v - bf2f(h));
}

__global__ __launch_bounds__(256)
void cvtA_k(const float* __restrict__ A, int lda, int M, int K,
            unsigned short* __restrict__ hi, unsigned short* __restrict__ lo) {
    int idx = blockIdx.x * 256 + threadIdx.x;      // float4 units
    int kq = K >> 2;
    if (idx >= M * kq) return;
    int r = idx / kq, c = (idx - r * kq) * 4;
    float4 v = *(const float4*)&A[(size_t)r * lda + c];
    ushort4 h, l;
    h.x = f2bf(v.x); l.x = f2bf(v.x - bf2f(h.x));
    h.y = f2bf(v.y); l.y = f2bf(v.y - bf2f(h.y));
    h.z = f2bf(v.z); l.z = f2bf(v.z - bf2f(h.z));
    h.w = f2bf(v.w); l.w = f2bf(v.w - bf2f(h.w));
    *(ushort4*)&hi[(size_t)r * K + c] = h;
    *(ushort4*)&lo[(size_t)r * K + c] = l;
}

// ---------------- per-(node,head) attention logits -----------------------
__global__ __launch_bounds__(256)
void attn_scores_k(const float* __restrict__ hp, const float* __restrict__ a_src,
                   const float* __restrict__ a_dst,
                   float* __restrict__ s_src, float* __restrict__ s_dst) {
    int gid = blockIdx.x * 256 + threadIdx.x;     // (n,h)
    if (gid >= N_NODES * NH) return;
    int h = gid & 7;
    const float4* hv = (const float4*)(hp + (size_t)gid * DH);
    const float4* av = (const float4*)(a_src + h * DH);
    const float4* dv = (const float4*)(a_dst + h * DH);
    float ss = 0.f, sd = 0.f;
    #pragma unroll
    for (int i = 0; i < 8; ++i) {
        float4 x = hv[i], a = av[i], d = dv[i];
        ss += x.x*a.x + x.y*a.y + x.z*a.z + x.w*a.w;
        sd += x.x*d.x + x.y*d.y + x.z*d.z + x.w*d.w;
    }
    s_src[gid] = ss; s_dst[gid] = sd;
}

// ---------------- CSR build ----------------------------------------------
__global__ __launch_bounds__(256)
void zero_k(int* p, int n) { int i = blockIdx.x*256 + threadIdx.x; if (i < n) p[i] = 0; }

__global__ __launch_bounds__(256)
void count_k(const int* __restrict__ dst, int* __restrict__ counts) {
    int e = blockIdx.x*256 + threadIdx.x;
    if (e >= ET) return;
    int d = (e < N_EDG) ? dst[e] : (e - N_EDG);
    d = min(max(d, 0), N_NODES - 1);
    atomicAdd(&counts[d], 1);
}

// hierarchical scan: 1024-elem blocks (wave shuffle scan), then block offsets
__global__ __launch_bounds__(1024)
void scan1_k(int* __restrict__ counts /*in: counts, out: excl*/,
             int* __restrict__ rowptr, int* __restrict__ blksum, int n) {
    __shared__ int wsum[16];
    const int tid = threadIdx.x, lane = tid & 63, wv = tid >> 6;
    const int i = blockIdx.x * 1024 + tid;
    int v = (i < n) ? counts[i] : 0;
    int s = v;
    #pragma unroll
    for (int off = 1; off < 64; off <<= 1) {
        int t = __shfl_up(s, off);
        if (lane >= off) s += t;
    }
    if (lane == 63) wsum[wv] = s;
    __syncthreads();
    if (wv == 0) {
        int ws = (lane < 16) ? wsum[lane] : 0;
        #pragma unroll
        for (int off = 1; off < 16; off <<= 1) {
            int t = __shfl_up(ws, off);
            if (lane >= off) ws += t;
        }
        if (lane < 16) wsum[lane] = ws;
    }
    __syncthreads();
    int excl = s - v + (wv > 0 ? wsum[wv - 1] : 0);
    if (i < n) { rowptr[i] = excl; counts[i] = excl; }
    if (tid == 0) blksum[blockIdx.x] = wsum[15];
}

__global__ __launch_bounds__(64)
void scan2_k(const int* __restrict__ blksum, int* __restrict__ blkoff, int nb) {
    int lane = threadIdx.x;
    int v = (lane < nb) ? blksum[lane] : 0;
    int s = v;
    #pragma unroll
    for (int off = 1; off < 64; off <<= 1) {
        int t = __shfl_up(s, off);
        if (lane >= off) s += t;
    }
    if (lane < nb) blkoff[lane] = s - v;
}

__global__ __launch_bounds__(256)
void scan3_k(int* __restrict__ rowptr, int* __restrict__ fillp,
             const int* __restrict__ blkoff, int n) {
    int i = blockIdx.x * 256 + threadIdx.x;
    if (i < n) {
        int off = blkoff[i >> 10];
        rowptr[i] += off;
        fillp[i]  += off;
    }
    if (i == 0) rowptr[n] = ET;   // total is exactly ET (all dsts clamped in-range)
}

__global__ __launch_bounds__(256)
void fill_k(const int* __restrict__ src, const int* __restrict__ dst,
            int* __restrict__ fillptr, int* __restrict__ srcs) {
    int e = blockIdx.x*256 + threadIdx.x;
    if (e >= ET) return;
    int s, d;
    if (e < N_EDG) { s = src[e]; d = dst[e]; } else { s = e - N_EDG; d = s; }
    s = min(max(s, 0), N_NODES - 1);
    d = min(max(d, 0), N_NODES - 1);
    int pos = atomicAdd(&fillptr[d], 1);
    pos = min(max(pos, 0), ET - 1);
    srcs[pos] = s;
}

// ---------------- segment-softmax aggregation: one wave per dst node -----
// no max-subtraction: logits bounded (|e| <~ 3), softmax shift-invariant
__global__ __launch_bounds__(256)
void agg_k(const int* __restrict__ rowptr, const int* __restrict__ srcs,
           const float* __restrict__ s_src, const float* __restrict__ s_dst,
           const float* __restrict__ hp, const float* __restrict__ bias,
           unsigned short* __restrict__ outhi, unsigned short* __restrict__ outlo,
           int out_off) {
    int wid  = (blockIdx.x * blockDim.x + threadIdx.x) >> 6;
    int lane = threadIdx.x & 63;
    if (wid >= N_NODES) return;
    const int n = wid;
    int r0 = rowptr[n], r1 = rowptr[n + 1];
    r0 = min(max(r0, 0), ET); r1 = min(max(r1, r0), ET);

    // pass 1: denominator. lane = slot*8 + h (8 edge-slots x 8 heads)
    const int h1 = lane & 7, slot = lane >> 3;
    const float sd1 = s_dst[n*NH + h1];
    float dn = 0.f;
    for (int i = r0 + slot; i < r1; i += 8) {
        int s = srcs[i];
        float ev = s_src[s*NH + h1] + sd1;
        ev = ev > 0.f ? ev : 0.2f * ev;
        dn += __expf(ev);
    }
    dn += __shfl_xor(dn, 8);
    dn += __shfl_xor(dn, 16);
    dn += __shfl_xor(dn, 32);

    // pass 2: weighted sum. lane owns head h2=lane>>3, dims 4*(lane&7)..+3
    const int h2 = lane >> 3;
    const float rdn = 1.f / __shfl(dn, h2);
    const float sd2 = __shfl(sd1, h2);
    float4 acc = make_float4(0.f,0.f,0.f,0.f);
    for (int i = r0; i < r1; ++i) {
        int s = srcs[i];
        float ev = s_src[s*NH + h2] + sd2;
        ev = ev > 0.f ? ev : 0.2f * ev;
        float ww = __expf(ev) * rdn;
        float4 v = *(const float4*)&hp[(size_t)s * HID + lane * 4];
        acc.x += ww*v.x; acc.y += ww*v.y; acc.z += ww*v.z; acc.w += ww*v.w;
    }
    float4 bb = *(const float4*)&bias[lane * 4];
    acc.x += bb.x; acc.y += bb.y; acc.z += bb.z; acc.w += bb.w;
    acc.x = acc.x > 0.f ? acc.x : expm1f(acc.x);   // ELU
    acc.y = acc.y > 0.f ? acc.y : expm1f(acc.y);
    acc.z = acc.z > 0.f ? acc.z : expm1f(acc.z);
    acc.w = acc.w > 0.f ? acc.w : expm1f(acc.w);
    ushort4 hh, ll;
    hh.x = f2bf(acc.x); ll.x = f2bf(acc.x - bf2f(hh.x));
    hh.y = f2bf(acc.y); ll.y = f2bf(acc.y - bf2f(hh.y));
    hh.z = f2bf(acc.z); ll.z = f2bf(acc.z - bf2f(hh.z));
    hh.w = f2bf(acc.w); ll.w = f2bf(acc.w - bf2f(hh.w));
    size_t o = (size_t)n * 768 + out_off + lane * 4;
    *(ushort4*)&outhi[o] = hh;
    *(ushort4*)&outlo[o] = ll;
}

// ---------------- semantic attention: scores -> softmax -> z -------------
__global__ __launch_bounds__(256)
void score_z_k(const float* t, const float* __restrict__ W2,
               const unsigned short* __restrict__ ehi,
               const unsigned short* __restrict__ elo,
               float* z) {
    int wid  = (blockIdx.x * blockDim.x + threadIdx.x) >> 6;
    int lane = threadIdx.x & 63;
    if (wid >= N_NODES) return;
    const int n = wid;
    float sc[3];
    #pragma unroll
    for (int p = 0; p < 3; ++p) {
        const float* tr = t + (size_t)(n*3 + p) * 128;
        float part = tr[lane] * W2[lane] + tr[64 + lane] * W2[64 + lane];
        #pragma unroll
        for (int o = 1; o < 64; o <<= 1) part += __shfl_xor(part, o);
        sc[p] = part;
    }
    float m  = fmaxf(sc[0], fmaxf(sc[1], sc[2]));
    float e0 = __expf(sc[0]-m), e1 = __expf(sc[1]-m), e2 = __expf(sc[2]-m);
    float rs = 1.f / (e0 + e1 + e2);
    e0 *= rs; e1 *= rs; e2 *= rs;
    const unsigned short* rh = ehi + (size_t)n * 768;
    const unsigned short* rl = elo + (size_t)n * 768;
    for (int c = lane; c < 256; c += 64) {
        float v0 = bf2f(rh[c])       + bf2f(rl[c]);
        float v1 = bf2f(rh[256 + c]) + bf2f(rl[256 + c]);
        float v2 = bf2f(rh[512 + c]) + bf2f(rl[512 + c]);
        z[(size_t)n*384 + c] = e0*v0 + e1*v1 + e2*v2;
    }
}

__global__ __launch_bounds__(256)
void logits_k(const float* __restrict__ hcls, const float* __restrict__ W2,
              const float* __restrict__ b2, float* __restrict__ out) {
    int gid = blockIdx.x*256 + threadIdx.x;
    if (gid >= N_NODES * 2) return;
    int n = gid >> 1, o = gid & 1;
    const float* hr = hcls + (size_t)n * 128;
    float a = b2[o];
    #pragma unroll 4
    for (int j = 0; j < 128; ++j) a += hr[j] * W2[j*2 + o];
    out[gid] = a;
}

// -------------------------------------------------------------------------
extern "C" void kernel_launch(void* const* d_in, const int* in_sizes, int n_in,
                              void* d_out, int out_size, void* d_ws, size_t ws_size,
                              hipStream_t stream) {
    (void)in_sizes; (void)n_in; (void)out_size; (void)ws_size;
    const float* x     = (const float*)d_in[0];
    const int*   edges = (const int*)  d_in[1];
    const float* projW = (const float*)d_in[2];
    const float* projb = (const float*)d_in[3];
    const float* gatW  = (const float*)d_in[4];
    const float* gatAs = (const float*)d_in[5];
    const float* gatAd = (const float*)d_in[6];
    const float* gatB  = (const float*)d_in[7];
    const float* semW1 = (const float*)d_in[8];
    const float* semb1 = (const float*)d_in[9];
    const float* semW2 = (const float*)d_in[10];
    const float* clsW1 = (const float*)d_in[11];
    const float* clsb1 = (const float*)d_in[12];
    const float* clsW2 = (const float*)d_in[13];
    const float* clsb2 = (const float*)d_in[14];
    float* out = (float*)d_out;

    // ---- byte-addressed arena, total ~263.5 MB ----
    char* base = (char*)d_ws;
    const size_t PLANE = (size_t)N_NODES * HID * 2;      // 25.6 MB (bf16 plane)
    unsigned short* h0hi = (unsigned short*)(base);
    unsigned short* h0lo = (unsigned short*)(base + PLANE);
    float*          hp   = (float*)(base + 2*PLANE);                  // 51.2 MB
    unsigned short* ehi  = (unsigned short*)(base + 4*PLANE);         // 76.8 MB
    unsigned short* elo  = (unsigned short*)(base + 7*PLANE);         // 76.8 MB
    char* small = base + 10*PLANE;                                    // at 256 MB
    float* ssrc = (float*)small;
    float* sdst = ssrc + (size_t)N_NODES*NH;
    int*   rowptr = (int*)(sdst + (size_t)N_NODES*NH);
    int*   fillp  = rowptr + (N_NODES + 2);
    int*   srcs   = fillp  + (N_NODES + 2);
    unsigned short* WThi = (unsigned short*)(srcs + ET);   // 256x256 bf16
    unsigned short* WTlo = WThi + 65536;
    int*   blksum = (int*)(WTlo + 65536);                  // [64]
    int*   blkoff = blksum + 64;                           // [64]
    // overlays:
    unsigned short* xhi = ehi;                              // before emb writes
    unsigned short* xlo = ehi + (size_t)N_NODES * 128;
    float* tbuf = (float*)base;                             // over h0pair+hp
    float* hcls = (float*)(base + 3*PLANE);                 // upper half of hp
    unsigned short* zhi = (unsigned short*)(base + 4*PLANE);// over emb (dead)
    unsigned short* zlo = zhi + (size_t)N_NODES * HID;

    dim3 blk(256);
    const int gx = (N_NODES + 127) / 128;     // 391
    const int NB = (N_NODES + 1023) / 1024;   // 49 scan blocks

    // ---- projection: h0pair = split(x @ projW + projb) ----
    cvtA_k<<<(N_NODES*32 + 255)/256, blk, 0, stream>>>(x, 128, N_NODES, 128, xhi, xlo);
    cvtW_k<<<(128*256 + 255)/256, blk, 0, stream>>>(projW, WThi, WTlo, 128, 256);
    mfma_gemm_k<256,0,1><<<dim3(gx,2), blk, 0, stream>>>(
        xhi, xlo, 128, WThi, WTlo, projb, nullptr, h0hi, h0lo, 256, N_NODES, 128);

    for (int p = 0; p < 3; ++p) {
        const int* esrc = edges + (size_t)p * 2 * N_EDG;
        const int* edst = esrc + N_EDG;
        zero_k <<<(N_NODES+255)/256, blk, 0, stream>>>(fillp, N_NODES);
        count_k<<<(ET+255)/256,      blk, 0, stream>>>(edst, fillp);
        scan1_k<<<NB, 1024, 0, stream>>>(fillp, rowptr, blksum, N_NODES);
        scan2_k<<<1, 64, 0, stream>>>(blksum, blkoff, NB);
        scan3_k<<<(N_NODES+255)/256, blk, 0, stream>>>(rowptr, fillp, blkoff, N_NODES);
        fill_k <<<(ET+255)/256,      blk, 0, stream>>>(esrc, edst, fillp, srcs);

        for (int l = 0; l < 2; ++l) {
            const int pl = p*2 + l;
            cvtW_k<<<(256*256 + 255)/256, blk, 0, stream>>>(
                gatW + (size_t)pl * HID * HID, WThi, WTlo, 256, 256);
            const unsigned short* Ah = (l == 0) ? h0hi : ehi + p*HID;
            const unsigned short* Al = (l == 0) ? h0lo : elo + p*HID;
            const int lda = (l == 0) ? HID : 3*HID;
            mfma_gemm_k<256,0,0><<<dim3(gx,2), blk, 0, stream>>>(
                Ah, Al, lda, WThi, WTlo, nullptr, hp, nullptr, nullptr, HID, N_NODES, HID);
            attn_scores_k<<<(N_NODES*NH+255)/256, blk, 0, stream>>>(
                hp, gatAs + pl*HID, gatAd + pl*HID, ssrc, sdst);
            agg_k<<<(N_NODES*64)/256, blk, 0, stream>>>(
                rowptr, srcs, ssrc, sdst, hp, gatB + pl*HID, ehi, elo, p*HID);
        }
    }

    // ---- semantic attention + classifier ----
    cvtW_k<<<(256*128 + 255)/256, blk, 0, stream>>>(semW1, WThi, WTlo, 256, 128);
    mfma_gemm_k<128,1,0><<<dim3((150000+127)/128, 1), blk, 0, stream>>>(
        ehi, elo, 256, WThi, WTlo, semb1, tbuf, nullptr, nullptr, 128, 150000, 256);
    score_z_k<<<(N_NODES*64)/256, blk, 0, stream>>>(tbuf, semW2, ehi, elo, tbuf);
    cvtA_k<<<(N_NODES*64 + 255)/256, blk, 0, stream>>>(tbuf, 384, N_NODES, 256, zhi, zlo);
    cvtW_k<<<(256*128 + 255)/256, blk, 0, stream>>>(clsW1, WThi, WTlo, 256, 128);
    mfma_gemm_k<128,2,0><<<dim3(gx, 1), blk, 0, stream>>>(
        zhi, zlo, 256, WThi, WTlo, clsb1, hcls, nullptr, nullptr, 128, N_NODES, 256);
    logits_k<<<(N_NODES*2+255)/256, blk, 0, stream>>>(hcls, clsW2, clsb2, out);
}

// Round 5
// 1698.965 us; speedup vs baseline: 2.1926x; 1.1009x over previous
//
#include <hip/hip_runtime.h>
#include <hip/hip_fp16.h>
#include <math.h>

#define N_NODES 50000
#define N_EDG   800000
#define ET      (N_EDG + N_NODES)   // +self loops
#define NH      8
#define DH      32
#define HID     256

typedef __attribute__((ext_vector_type(8))) short bf16x8;
typedef __attribute__((ext_vector_type(4))) float f32x4;

__device__ __forceinline__ unsigned short f2bf(float x) {
    unsigned u = __float_as_uint(x);
    u += 0x7FFF + ((u >> 16) & 1);          // RNE
    return (unsigned short)(u >> 16);
}
__device__ __forceinline__ float bf2f(unsigned short h) {
    return __uint_as_float(((unsigned)h) << 16);
}
__device__ __forceinline__ void split8(const float4& a, const float4& b,
                                       uint4& hi, uint4& lo) {
    float v[8] = {a.x,a.y,a.z,a.w,b.x,b.y,b.z,b.w};
    unsigned short h[8], l[8];
    #pragma unroll
    for (int i = 0; i < 8; ++i) { h[i] = f2bf(v[i]); l[i] = f2bf(v[i] - bf2f(h[i])); }
    hi = make_uint4(h[0]|((unsigned)h[1]<<16), h[2]|((unsigned)h[3]<<16),
                    h[4]|((unsigned)h[5]<<16), h[6]|((unsigned)h[7]<<16));
    lo = make_uint4(l[0]|((unsigned)l[1]<<16), l[2]|((unsigned)l[3]<<16),
                    l[4]|((unsigned)l[5]<<16), l[6]|((unsigned)l[7]<<16));
}

// ---------------- bf16x3 MFMA GEMM --------------------------------------
// C[M,NC] = act(A @ W + bias). A: bf16 hi/lo planes (A32=0) or f32 split
// in-register during staging (A32=1). W: transposed hi/lo planes WT[NC][K].
// 128x128 tile, 256 thr, BK=32, software-pipelined global prefetch.
// OUTMODE: 0 = f32 C, 1 = bf16 hi/lo planes, 2 = fp16
#define SK 40   // padded LDS row stride (elems): <=2-way banks (free)
template<int NC, int ACT, int OUTMODE, int A32>
__global__ __launch_bounds__(256)
void mfma_gemm_k(const float* __restrict__ A32p,
                 const unsigned short* __restrict__ Ahi,
                 const unsigned short* __restrict__ Alo, int lda,
                 const unsigned short* __restrict__ WThi,
                 const unsigned short* __restrict__ WTlo,
                 const float* __restrict__ bias,
                 float* __restrict__ C, __half* __restrict__ Ch,
                 unsigned short* __restrict__ Chi, unsigned short* __restrict__ Clo,
                 int ldc, int M, int K) {
    __shared__ unsigned short sAh[128*SK], sAl[128*SK], sBh[128*SK], sBl[128*SK];
    const int tid  = threadIdx.x;
    const int lane = tid & 63;
    const int w    = tid >> 6;
    const int wr   = w >> 1, wc = w & 1;
    const int r0   = blockIdx.x * 128;
    const int c0   = blockIdx.y * 128;
    const int l15  = lane & 15, q = lane >> 4;

    const int srow = tid >> 2, slot = tid & 3;
    const size_t gaB0 = (size_t)min(r0 + srow,      M - 1) * lda + slot * 8;
    const size_t gaB1 = (size_t)min(r0 + srow + 64, M - 1) * lda + slot * 8;
    const size_t gbB0 = (size_t)(c0 + srow)      * K + slot * 8;
    const size_t gbB1 = (size_t)(c0 + srow + 64) * K + slot * 8;
    const int    ld0  = srow * SK + slot * 8;
    const int    ld1  = (srow + 64) * SK + slot * 8;

    f32x4 acc[4][4];
    #pragma unroll
    for (int i = 0; i < 4; ++i)
        #pragma unroll
        for (int j = 0; j < 4; ++j) acc[i][j] = (f32x4){0.f, 0.f, 0.f, 0.f};

    uint4 rAh0, rAh1, rAl0, rAl1, rBh0, rBh1, rBl0, rBl1;
    float4 rF0a, rF0b, rF1a, rF1b;
    auto glb_load = [&](int kc) {
        if constexpr (A32) {
            rF0a = *(const float4*)&A32p[gaB0 + kc];
            rF0b = *(const float4*)&A32p[gaB0 + kc + 4];
            rF1a = *(const float4*)&A32p[gaB1 + kc];
            rF1b = *(const float4*)&A32p[gaB1 + kc + 4];
        } else {
            rAh0 = *(const uint4*)&Ahi[gaB0 + kc];
            rAh1 = *(const uint4*)&Ahi[gaB1 + kc];
            rAl0 = *(const uint4*)&Alo[gaB0 + kc];
            rAl1 = *(const uint4*)&Alo[gaB1 + kc];
        }
        rBh0 = *(const uint4*)&WThi[gbB0 + kc];
        rBh1 = *(const uint4*)&WThi[gbB1 + kc];
        rBl0 = *(const uint4*)&WTlo[gbB0 + kc];
        rBl1 = *(const uint4*)&WTlo[gbB1 + kc];
    };

    const int nsteps = K >> 5;
    glb_load(0);
    for (int s = 0; s < nsteps; ++s) {
        __syncthreads();                       // prior step's LDS reads done
        if constexpr (A32) {
            uint4 h0v, l0v, h1v, l1v;
            split8(rF0a, rF0b, h0v, l0v);
            split8(rF1a, rF1b, h1v, l1v);
            *(uint4*)&sAh[ld0] = h0v; *(uint4*)&sAh[ld1] = h1v;
            *(uint4*)&sAl[ld0] = l0v; *(uint4*)&sAl[ld1] = l1v;
        } else {
            *(uint4*)&sAh[ld0] = rAh0; *(uint4*)&sAh[ld1] = rAh1;
            *(uint4*)&sAl[ld0] = rAl0; *(uint4*)&sAl[ld1] = rAl1;
        }
        *(uint4*)&sBh[ld0] = rBh0; *(uint4*)&sBh[ld1] = rBh1;
        *(uint4*)&sBl[ld0] = rBl0; *(uint4*)&sBl[ld1] = rBl1;
        __syncthreads();
        if (s + 1 < nsteps) glb_load((s + 1) << 5);   // in flight during MFMA

        bf16x8 fAh[4], fAl[4];
        #pragma unroll
        for (int t = 0; t < 4; ++t) {
            int ra = (wr*64 + t*16 + l15) * SK + q*8;
            fAh[t] = *(const bf16x8*)&sAh[ra];
            fAl[t] = *(const bf16x8*)&sAl[ra];
        }
        #pragma unroll
        for (int nt = 0; nt < 4; ++nt) {
            int rb = (wc*64 + nt*16 + l15) * SK + q*8;
            bf16x8 fBh = *(const bf16x8*)&sBh[rb];
            bf16x8 fBl = *(const bf16x8*)&sBl[rb];
            #pragma unroll
            for (int mt = 0; mt < 4; ++mt) {
                acc[mt][nt] = __builtin_amdgcn_mfma_f32_16x16x32_bf16(fAh[mt], fBh, acc[mt][nt], 0, 0, 0);
                acc[mt][nt] = __builtin_amdgcn_mfma_f32_16x16x32_bf16(fAh[mt], fBl, acc[mt][nt], 0, 0, 0);
                acc[mt][nt] = __builtin_amdgcn_mfma_f32_16x16x32_bf16(fAl[mt], fBh, acc[mt][nt], 0, 0, 0);
            }
        }
    }
    // epilogue: C/D layout col=lane&15, row=(lane>>4)*4+reg  [m89-verified]
    #pragma unroll
    for (int mt = 0; mt < 4; ++mt)
        #pragma unroll
        for (int nt = 0; nt < 4; ++nt) {
            int col = c0 + wc*64 + nt*16 + l15;
            float bb = bias ? bias[col] : 0.f;
            #pragma unroll
            for (int r = 0; r < 4; ++r) {
                int grow = r0 + wr*64 + mt*16 + q*4 + r;
                if (grow < M) {
                    float v = acc[mt][nt][r] + bb;
                    if (ACT == 1) v = tanhf(v);
                    else if (ACT == 2) v = fmaxf(v, 0.f);
                    size_t o = (size_t)grow * ldc + col;
                    if (OUTMODE == 1) {
                        unsigned short h = f2bf(v);
                        Chi[o] = h;
                        Clo[o] = f2bf(v - bf2f(h));
                    } else if (OUTMODE == 2) {
                        Ch[o] = __float2half(v);
                    } else {
                        C[o] = v;
                    }
                }
            }
        }
}

// ---------------- conversions -------------------------------------------
__global__ __launch_bounds__(256)
void cvtW_k(const float* __restrict__ W, unsigned short* __restrict__ WThi,
            unsigned short* __restrict__ WTlo, int K, int N) {
    int idx = blockIdx.x * 256 + threadIdx.x;
    if (idx >= K * N) return;
    int k = idx / N, n = idx - k * N;
    float v = W[idx];
    unsigned short h = f2bf(v);
    WThi[n * K + k] = h;
    WTlo[n * K + k] = f2bf(v - bf2f(h));
}

// ---------------- per-(node,head) attention logits (fp16 hp) -------------
__global__ __launch_bounds__(256)
void attn_scores_k(const __half* __restrict__ hp, const float* __restrict__ a_src,
                   const float* __restrict__ a_dst,
                   float* __restrict__ s_src, float* __restrict__ s_dst) {
    int gid = blockIdx.x * 256 + threadIdx.x;     // (n,h)
    if (gid >= N_NODES * NH) return;
    int h = gid & 7;
    const __half2* hv = (const __half2*)(hp + (size_t)gid * DH);
    const float* a = a_src + h * DH;
    const float* d = a_dst + h * DH;
    float ss = 0.f, sd = 0.f;
    #pragma unroll
    for (int j = 0; j < 8; ++j) {
        float4 av = ((const float4*)a)[j], dv = ((const float4*)d)[j];
        float2 f0 = __half22float2(hv[2*j]);
        float2 f1 = __half22float2(hv[2*j + 1]);
        ss += f0.x*av.x + f0.y*av.y + f1.x*av.z + f1.y*av.w;
        sd += f0.x*dv.x + f0.y*dv.y + f1.x*dv.z + f1.y*dv.w;
    }
    s_src[gid] = ss; s_dst[gid] = sd;
}

// ---------------- CSR build ----------------------------------------------
__global__ __launch_bounds__(256)
void zero_k(int* p, int n) { int i = blockIdx.x*256 + threadIdx.x; if (i < n) p[i] = 0; }

__global__ __launch_bounds__(256)
void count_k(const int* __restrict__ dst, int* __restrict__ counts) {
    int e = blockIdx.x*256 + threadIdx.x;
    if (e >= ET) return;
    int d = (e < N_EDG) ? dst[e] : (e - N_EDG);
    d = min(max(d, 0), N_NODES - 1);
    atomicAdd(&counts[d], 1);
}

// hierarchical scan: 1024-elem blocks (wave shuffle scan), then block offsets
__global__ __launch_bounds__(1024)
void scan1_k(int* __restrict__ counts, int* __restrict__ rowptr,
             int* __restrict__ blksum, int n) {
    __shared__ int wsum[16];
    const int tid = threadIdx.x, lane = tid & 63, wv = tid >> 6;
    const int i = blockIdx.x * 1024 + tid;
    int v = (i < n) ? counts[i] : 0;
    int s = v;
    #pragma unroll
    for (int off = 1; off < 64; off <<= 1) {
        int t = __shfl_up(s, off);
        if (lane >= off) s += t;
    }
    if (lane == 63) wsum[wv] = s;
    __syncthreads();
    if (wv == 0) {
        int ws = (lane < 16) ? wsum[lane] : 0;
        #pragma unroll
        for (int off = 1; off < 16; off <<= 1) {
            int t = __shfl_up(ws, off);
            if (lane >= off) ws += t;
        }
        if (lane < 16) wsum[lane] = ws;
    }
    __syncthreads();
    int excl = s - v + (wv > 0 ? wsum[wv - 1] : 0);
    if (i < n) { rowptr[i] = excl; counts[i] = excl; }
    if (tid == 0) blksum[blockIdx.x] = wsum[15];
}

__global__ __launch_bounds__(64)
void scan2_k(const int* __restrict__ blksum, int* __restrict__ blkoff, int nb) {
    int lane = threadIdx.x;
    int v = (lane < nb) ? blksum[lane] : 0;
    int s = v;
    #pragma unroll
    for (int off = 1; off < 64; off <<= 1) {
        int t = __shfl_up(s, off);
        if (lane >= off) s += t;
    }
    if (lane < nb) blkoff[lane] = s - v;
}

__global__ __launch_bounds__(256)
void scan3_k(int* __restrict__ rowptr, int* __restrict__ fillp,
             const int* __restrict__ blkoff, int n) {
    int i = blockIdx.x * 256 + threadIdx.x;
    if (i < n) {
        int off = blkoff[i >> 10];
        rowptr[i] += off;
        fillp[i]  += off;
    }
    if (i == 0) rowptr[n] = ET;
}

__global__ __launch_bounds__(256)
void fill_k(const int* __restrict__ src, const int* __restrict__ dst,
            int* __restrict__ fillptr, int* __restrict__ srcs) {
    int e = blockIdx.x*256 + threadIdx.x;
    if (e >= ET) return;
    int s, d;
    if (e < N_EDG) { s = src[e]; d = dst[e]; } else { s = e - N_EDG; d = s; }
    s = min(max(s, 0), N_NODES - 1);
    d = min(max(d, 0), N_NODES - 1);
    int pos = atomicAdd(&fillptr[d], 1);
    pos = min(max(pos, 0), ET - 1);
    srcs[pos] = s;
}

// ---------------- segment-softmax aggregation: one wave per dst node -----
// fp16 hp gather (512 B/row); scores fp32; no max-subtraction (|e| <~ 3)
__global__ __launch_bounds__(256)
void agg_k(const int* __restrict__ rowptr, const int* __restrict__ srcs,
           const float* __restrict__ s_src, const float* __restrict__ s_dst,
           const __half* __restrict__ hp, const float* __restrict__ bias,
           unsigned short* __restrict__ outhi, unsigned short* __restrict__ outlo,
           int out_off) {
    int wid  = (blockIdx.x * blockDim.x + threadIdx.x) >> 6;
    int lane = threadIdx.x & 63;
    if (wid >= N_NODES) return;
    const int n = wid;
    int r0 = rowptr[n], r1 = rowptr[n + 1];
    r0 = min(max(r0, 0), ET); r1 = min(max(r1, r0), ET);

    // pass 1: denominator. lane = slot*8 + h (8 edge-slots x 8 heads)
    const int h1 = lane & 7, slot = lane >> 3;
    const float sd1 = s_dst[n*NH + h1];
    float dn = 0.f;
    for (int i = r0 + slot; i < r1; i += 8) {
        int s = srcs[i];
        float ev = s_src[s*NH + h1] + sd1;
        ev = ev > 0.f ? ev : 0.2f * ev;
        dn += __expf(ev);
    }
    dn += __shfl_xor(dn, 8);
    dn += __shfl_xor(dn, 16);
    dn += __shfl_xor(dn, 32);

    // pass 2: weighted sum. lane owns head h2=lane>>3, dims 4*(lane&7)..+3
    const int h2 = lane >> 3;
    const float rdn = 1.f / __shfl(dn, h2);
    const float sd2 = __shfl(sd1, h2);
    float4 acc = make_float4(0.f,0.f,0.f,0.f);
    for (int i = r0; i < r1; ++i) {
        int s = srcs[i];
        float ev = s_src[s*NH + h2] + sd2;
        ev = ev > 0.f ? ev : 0.2f * ev;
        float ww = __expf(ev) * rdn;
        const __half2* hv = (const __half2*)(hp + (size_t)s * HID + lane * 4);
        float2 f0 = __half22float2(hv[0]);
        float2 f1 = __half22float2(hv[1]);
        acc.x += ww*f0.x; acc.y += ww*f0.y; acc.z += ww*f1.x; acc.w += ww*f1.y;
    }
    float4 bb = *(const float4*)&bias[lane * 4];
    acc.x += bb.x; acc.y += bb.y; acc.z += bb.z; acc.w += bb.w;
    acc.x = acc.x > 0.f ? acc.x : expm1f(acc.x);   // ELU
    acc.y = acc.y > 0.f ? acc.y : expm1f(acc.y);
    acc.z = acc.z > 0.f ? acc.z : expm1f(acc.z);
    acc.w = acc.w > 0.f ? acc.w : expm1f(acc.w);
    ushort4 hh, ll;
    hh.x = f2bf(acc.x); ll.x = f2bf(acc.x - bf2f(hh.x));
    hh.y = f2bf(acc.y); ll.y = f2bf(acc.y - bf2f(hh.y));
    hh.z = f2bf(acc.z); ll.z = f2bf(acc.z - bf2f(hh.z));
    hh.w = f2bf(acc.w); ll.w = f2bf(acc.w - bf2f(hh.w));
    size_t o = (size_t)n * 768 + out_off + lane * 4;
    *(ushort4*)&outhi[o] = hh;
    *(ushort4*)&outlo[o] = ll;
}

// ---------------- semantic attention: scores -> softmax -> z -------------
__global__ __launch_bounds__(256)
void score_z_k(const float* t, const float* __restrict__ W2,
               const unsigned short* __restrict__ ehi,
               const unsigned short* __restrict__ elo,
               float* z) {
    int wid  = (blockIdx.x * blockDim.x + threadIdx.x) >> 6;
    int lane = threadIdx.x & 63;
    if (wid >= N_NODES) return;
    const int n = wid;
    float sc[3];
    #pragma unroll
    for (int p = 0; p < 3; ++p) {
        const float* tr = t + (size_t)(n*3 + p) * 128;
        float part = tr[lane] * W2[lane] + tr[64 + lane] * W2[64 + lane];
        #pragma unroll
        for (int o = 1; o < 64; o <<= 1) part += __shfl_xor(part, o);
        sc[p] = part;
    }
    float m  = fmaxf(sc[0], fmaxf(sc[1], sc[2]));
    float e0 = __expf(sc[0]-m), e1 = __expf(sc[1]-m), e2 = __expf(sc[2]-m);
    float rs = 1.f / (e0 + e1 + e2);
    e0 *= rs; e1 *= rs; e2 *= rs;
    const unsigned short* rh = ehi + (size_t)n * 768;
    const unsigned short* rl = elo + (size_t)n * 768;
    for (int c = lane; c < 256; c += 64) {
        float v0 = bf2f(rh[c])       + bf2f(rl[c]);
        float v1 = bf2f(rh[256 + c]) + bf2f(rl[256 + c]);
        float v2 = bf2f(rh[512 + c]) + bf2f(rl[512 + c]);
        z[(size_t)n*384 + c] = e0*v0 + e1*v1 + e2*v2;   // own row of t-arena
    }
}

__global__ __launch_bounds__(256)
void logits_k(const float* __restrict__ hcls, const float* __restrict__ W2,
              const float* __restrict__ b2, float* __restrict__ out) {
    int gid = blockIdx.x*256 + threadIdx.x;
    if (gid >= N_NODES * 2) return;
    int n = gid >> 1, o = gid & 1;
    const float* hr = hcls + (size_t)n * 128;
    float a = b2[o];
    #pragma unroll 4
    for (int j = 0; j < 128; ++j) a += hr[j] * W2[j*2 + o];
    out[gid] = a;
}

// -------------------------------------------------------------------------
extern "C" void kernel_launch(void* const* d_in, const int* in_sizes, int n_in,
                              void* d_out, int out_size, void* d_ws, size_t ws_size,
                              hipStream_t stream) {
    (void)in_sizes; (void)n_in; (void)out_size; (void)ws_size;
    const float* x     = (const float*)d_in[0];
    const int*   edges = (const int*)  d_in[1];
    const float* projW = (const float*)d_in[2];
    const float* projb = (const float*)d_in[3];
    const float* gatW  = (const float*)d_in[4];
    const float* gatAs = (const float*)d_in[5];
    const float* gatAd = (const float*)d_in[6];
    const float* gatB  = (const float*)d_in[7];
    const float* semW1 = (const float*)d_in[8];
    const float* semb1 = (const float*)d_in[9];
    const float* semW2 = (const float*)d_in[10];
    const float* clsW1 = (const float*)d_in[11];
    const float* clsb1 = (const float*)d_in[12];
    const float* clsW2 = (const float*)d_in[13];
    const float* clsb2 = (const float*)d_in[14];
    float* out = (float*)d_out;

    // ---- byte-addressed arena, high-water ~263.5 MB (same as passing R3) ----
    char* base = (char*)d_ws;
    const size_t PLANE = (size_t)N_NODES * HID * 2;      // 25.6 MB
    unsigned short* h0hi = (unsigned short*)(base);
    unsigned short* h0lo = (unsigned short*)(base + PLANE);
    __half*         hp16 = (__half*)(base + 2*PLANE);                 // 25.6 MB
    unsigned short* ehi  = (unsigned short*)(base + 4*PLANE);         // 76.8 MB
    unsigned short* elo  = (unsigned short*)(base + 7*PLANE);         // 76.8 MB
    char* small = base + 10*PLANE;
    float* ssrc = (float*)small;
    float* sdst = ssrc + (size_t)N_NODES*NH;
    int*   rowptr = (int*)(sdst + (size_t)N_NODES*NH);
    int*   fillp  = rowptr + (N_NODES + 2);
    int*   srcs   = fillp  + (N_NODES + 2);
    unsigned short* WThi = (unsigned short*)(srcs + ET);
    unsigned short* WTlo = WThi + 65536;
    int*   blksum = (int*)(WTlo + 65536);
    int*   blkoff = blksum + 64;
    // final-stage overlays (h0pair/hp16 dead):
    float* tbuf = (float*)base;                  // [N,3,128] f32 = [0, 3*PLANE)
    float* hcls = (float*)(base + 3*PLANE);      // [N,128] f32

    dim3 blk(256);
    const int gx = (N_NODES + 127) / 128;     // 391
    const int NB = (N_NODES + 1023) / 1024;   // 49 scan blocks

    // ---- projection: h0pair = split(x @ projW + projb), x f32 staged ----
    cvtW_k<<<(128*256 + 255)/256, blk, 0, stream>>>(projW, WThi, WTlo, 128, 256);
    mfma_gemm_k<256,0,1,1><<<dim3(gx,2), blk, 0, stream>>>(
        x, nullptr, nullptr, 128, WThi, WTlo, projb,
        nullptr, nullptr, h0hi, h0lo, 256, N_NODES, 128);

    for (int p = 0; p < 3; ++p) {
        const int* esrc = edges + (size_t)p * 2 * N_EDG;
        const int* edst = esrc + N_EDG;
        zero_k <<<(N_NODES+255)/256, blk, 0, stream>>>(fillp, N_NODES);
        count_k<<<(ET+255)/256,      blk, 0, stream>>>(edst, fillp);
        scan1_k<<<NB, 1024, 0, stream>>>(fillp, rowptr, blksum, N_NODES);
        scan2_k<<<1, 64, 0, stream>>>(blksum, blkoff, NB);
        scan3_k<<<(N_NODES+255)/256, blk, 0, stream>>>(rowptr, fillp, blkoff, N_NODES);
        fill_k <<<(ET+255)/256,      blk, 0, stream>>>(esrc, edst, fillp, srcs);

        for (int l = 0; l < 2; ++l) {
            const int pl = p*2 + l;
            cvtW_k<<<(256*256 + 255)/256, blk, 0, stream>>>(
                gatW + (size_t)pl * HID * HID, WThi, WTlo, 256, 256);
            const unsigned short* Ah = (l == 0) ? h0hi : ehi + p*HID;
            const unsigned short* Al = (l == 0) ? h0lo : elo + p*HID;
            const int lda = (l == 0) ? HID : 3*HID;
            mfma_gemm_k<256,0,2,0><<<dim3(gx,2), blk, 0, stream>>>(
                nullptr, Ah, Al, lda, WThi, WTlo, nullptr,
                nullptr, hp16, nullptr, nullptr, HID, N_NODES, HID);
            attn_scores_k<<<(N_NODES*NH+255)/256, blk, 0, stream>>>(
                hp16, gatAs + pl*HID, gatAd + pl*HID, ssrc, sdst);
            agg_k<<<(N_NODES*64)/256, blk, 0, stream>>>(
                rowptr, srcs, ssrc, sdst, hp16, gatB + pl*HID, ehi, elo, p*HID);
        }
    }

    // ---- semantic attention + classifier ----
    cvtW_k<<<(256*128 + 255)/256, blk, 0, stream>>>(semW1, WThi, WTlo, 256, 128);
    mfma_gemm_k<128,1,0,0><<<dim3((150000+127)/128, 1), blk, 0, stream>>>(
        nullptr, ehi, elo, 256, WThi, WTlo, semb1,
        tbuf, nullptr, nullptr, nullptr, 128, 150000, 256);
    score_z_k<<<(N_NODES*64)/256, blk, 0, stream>>>(tbuf, semW2, ehi, elo, tbuf);
    cvtW_k<<<(256*128 + 255)/256, blk, 0, stream>>>(clsW1, WThi, WTlo, 256, 128);
    mfma_gemm_k<128,2,0,1><<<dim3(gx, 1), blk, 0, stream>>>(
        tbuf, nullptr, nullptr, 384, WThi, WTlo, clsb1,
        hcls, nullptr, nullptr, nullptr, 128, N_NODES, 256);
    logits_k<<<(N_NODES*2+255)/256, blk, 0, stream>>>(hcls, clsW2, clsb2, out);
}

// Round 6
// 1475.743 us; speedup vs baseline: 2.5242x; 1.1513x over previous
//
#include <hip/hip_runtime.h>
#include <hip/hip_fp16.h>
#include <math.h>

#define N_NODES 50000
#define N_EDG   800000
#define ET      (N_EDG + N_NODES)   // +self loops
#define NH      8
#define DH      32
#define HID     256

typedef __attribute__((ext_vector_type(8))) short bf16x8;
typedef __attribute__((ext_vector_type(4))) float f32x4;

__device__ __forceinline__ unsigned short f2bf(float x) {
    unsigned u = __float_as_uint(x);
    u += 0x7FFF + ((u >> 16) & 1);          // RNE
    return (unsigned short)(u >> 16);
}
__device__ __forceinline__ float bf2f(unsigned short h) {
    return __uint_as_float(((unsigned)h) << 16);
}
__device__ __forceinline__ void split8(const float4& a, const float4& b,
                                       uint4& hi, uint4& lo) {
    float v[8] = {a.x,a.y,a.z,a.w,b.x,b.y,b.z,b.w};
    unsigned short h[8], l[8];
    #pragma unroll
    for (int i = 0; i < 8; ++i) { h[i] = f2bf(v[i]); l[i] = f2bf(v[i] - bf2f(h[i])); }
    hi = make_uint4(h[0]|((unsigned)h[1]<<16), h[2]|((unsigned)h[3]<<16),
                    h[4]|((unsigned)h[5]<<16), h[6]|((unsigned)h[7]<<16));
    lo = make_uint4(l[0]|((unsigned)l[1]<<16), l[2]|((unsigned)l[3]<<16),
                    l[4]|((unsigned)l[5]<<16), l[6]|((unsigned)l[7]<<16));
}

// ---------------- bf16x3 MFMA GEMM --------------------------------------
// C[M,NC] = act(A @ W + bias). A: bf16 hi/lo planes (A32=0) or f32 split
// in-register during staging (A32=1). W: transposed hi/lo planes WT[NC][K].
// 128x128 tile, 256 thr, BK=32, software-pipelined global prefetch.
// OUTMODE: 0 = f32 C, 1 = bf16 hi/lo planes, 2 = fp16
#define SK 40   // padded LDS row stride (elems): <=2-way banks (free)
template<int NC, int ACT, int OUTMODE, int A32>
__global__ __launch_bounds__(256)
void mfma_gemm_k(const float* __restrict__ A32p,
                 const unsigned short* __restrict__ Ahi,
                 const unsigned short* __restrict__ Alo, int lda,
                 const unsigned short* __restrict__ WThi,
                 const unsigned short* __restrict__ WTlo,
                 const float* __restrict__ bias,
                 float* __restrict__ C, __half* __restrict__ Ch,
                 unsigned short* __restrict__ Chi, unsigned short* __restrict__ Clo,
                 int ldc, int M, int K) {
    __shared__ unsigned short sAh[128*SK], sAl[128*SK], sBh[128*SK], sBl[128*SK];
    const int tid  = threadIdx.x;
    const int lane = tid & 63;
    const int w    = tid >> 6;
    const int wr   = w >> 1, wc = w & 1;
    const int r0   = blockIdx.x * 128;
    const int c0   = blockIdx.y * 128;
    const int l15  = lane & 15, q = lane >> 4;

    const int srow = tid >> 2, slot = tid & 3;
    const size_t gaB0 = (size_t)min(r0 + srow,      M - 1) * lda + slot * 8;
    const size_t gaB1 = (size_t)min(r0 + srow + 64, M - 1) * lda + slot * 8;
    const size_t gbB0 = (size_t)(c0 + srow)      * K + slot * 8;
    const size_t gbB1 = (size_t)(c0 + srow + 64) * K + slot * 8;
    const int    ld0  = srow * SK + slot * 8;
    const int    ld1  = (srow + 64) * SK + slot * 8;

    f32x4 acc[4][4];
    #pragma unroll
    for (int i = 0; i < 4; ++i)
        #pragma unroll
        for (int j = 0; j < 4; ++j) acc[i][j] = (f32x4){0.f, 0.f, 0.f, 0.f};

    uint4 rAh0, rAh1, rAl0, rAl1, rBh0, rBh1, rBl0, rBl1;
    float4 rF0a, rF0b, rF1a, rF1b;
    auto glb_load = [&](int kc) {
        if constexpr (A32) {
            rF0a = *(const float4*)&A32p[gaB0 + kc];
            rF0b = *(const float4*)&A32p[gaB0 + kc + 4];
            rF1a = *(const float4*)&A32p[gaB1 + kc];
            rF1b = *(const float4*)&A32p[gaB1 + kc + 4];
        } else {
            rAh0 = *(const uint4*)&Ahi[gaB0 + kc];
            rAh1 = *(const uint4*)&Ahi[gaB1 + kc];
            rAl0 = *(const uint4*)&Alo[gaB0 + kc];
            rAl1 = *(const uint4*)&Alo[gaB1 + kc];
        }
        rBh0 = *(const uint4*)&WThi[gbB0 + kc];
        rBh1 = *(const uint4*)&WThi[gbB1 + kc];
        rBl0 = *(const uint4*)&WTlo[gbB0 + kc];
        rBl1 = *(const uint4*)&WTlo[gbB1 + kc];
    };

    const int nsteps = K >> 5;
    glb_load(0);
    for (int s = 0; s < nsteps; ++s) {
        __syncthreads();                       // prior step's LDS reads done
        if constexpr (A32) {
            uint4 h0v, l0v, h1v, l1v;
            split8(rF0a, rF0b, h0v, l0v);
            split8(rF1a, rF1b, h1v, l1v);
            *(uint4*)&sAh[ld0] = h0v; *(uint4*)&sAh[ld1] = h1v;
            *(uint4*)&sAl[ld0] = l0v; *(uint4*)&sAl[ld1] = l1v;
        } else {
            *(uint4*)&sAh[ld0] = rAh0; *(uint4*)&sAh[ld1] = rAh1;
            *(uint4*)&sAl[ld0] = rAl0; *(uint4*)&sAl[ld1] = rAl1;
        }
        *(uint4*)&sBh[ld0] = rBh0; *(uint4*)&sBh[ld1] = rBh1;
        *(uint4*)&sBl[ld0] = rBl0; *(uint4*)&sBl[ld1] = rBl1;
        __syncthreads();
        if (s + 1 < nsteps) glb_load((s + 1) << 5);   // in flight during MFMA

        bf16x8 fAh[4], fAl[4];
        #pragma unroll
        for (int t = 0; t < 4; ++t) {
            int ra = (wr*64 + t*16 + l15) * SK + q*8;
            fAh[t] = *(const bf16x8*)&sAh[ra];
            fAl[t] = *(const bf16x8*)&sAl[ra];
        }
        #pragma unroll
        for (int nt = 0; nt < 4; ++nt) {
            int rb = (wc*64 + nt*16 + l15) * SK + q*8;
            bf16x8 fBh = *(const bf16x8*)&sBh[rb];
            bf16x8 fBl = *(const bf16x8*)&sBl[rb];
            #pragma unroll
            for (int mt = 0; mt < 4; ++mt) {
                acc[mt][nt] = __builtin_amdgcn_mfma_f32_16x16x32_bf16(fAh[mt], fBh, acc[mt][nt], 0, 0, 0);
                acc[mt][nt] = __builtin_amdgcn_mfma_f32_16x16x32_bf16(fAh[mt], fBl, acc[mt][nt], 0, 0, 0);
                acc[mt][nt] = __builtin_amdgcn_mfma_f32_16x16x32_bf16(fAl[mt], fBh, acc[mt][nt], 0, 0, 0);
            }
        }
    }
    // epilogue: C/D layout col=lane&15, row=(lane>>4)*4+reg  [m89-verified]
    #pragma unroll
    for (int mt = 0; mt < 4; ++mt)
        #pragma unroll
        for (int nt = 0; nt < 4; ++nt) {
            int col = c0 + wc*64 + nt*16 + l15;
            float bb = bias ? bias[col] : 0.f;
            #pragma unroll
            for (int r = 0; r < 4; ++r) {
                int grow = r0 + wr*64 + mt*16 + q*4 + r;
                if (grow < M) {
                    float v = acc[mt][nt][r] + bb;
                    if (ACT == 1) v = tanhf(v);
                    else if (ACT == 2) v = fmaxf(v, 0.f);
                    size_t o = (size_t)grow * ldc + col;
                    if (OUTMODE == 1) {
                        unsigned short h = f2bf(v);
                        Chi[o] = h;
                        Clo[o] = f2bf(v - bf2f(h));
                    } else if (OUTMODE == 2) {
                        Ch[o] = __float2half(v);
                    } else {
                        C[o] = v;
                    }
                }
            }
        }
}

// ---------------- conversions -------------------------------------------
__global__ __launch_bounds__(256)
void cvtW_k(const float* __restrict__ W, unsigned short* __restrict__ WThi,
            unsigned short* __restrict__ WTlo, int K, int N) {
    int idx = blockIdx.x * 256 + threadIdx.x;
    if (idx >= K * N) return;
    int k = idx / N, n = idx - k * N;
    float v = W[idx];
    unsigned short h = f2bf(v);
    WThi[n * K + k] = h;
    WTlo[n * K + k] = f2bf(v - bf2f(h));
}

// ---------------- per-(node,head) attention logits (fp16 hp) -------------
__global__ __launch_bounds__(256)
void attn_scores_k(const __half* __restrict__ hp, const float* __restrict__ a_src,
                   const float* __restrict__ a_dst,
                   float* __restrict__ s_src, float* __restrict__ s_dst) {
    int gid = blockIdx.x * 256 + threadIdx.x;     // (n,h)
    if (gid >= N_NODES * NH) return;
    int h = gid & 7;
    const __half2* hv = (const __half2*)(hp + (size_t)gid * DH);
    const float* a = a_src + h * DH;
    const float* d = a_dst + h * DH;
    float ss = 0.f, sd = 0.f;
    #pragma unroll
    for (int j = 0; j < 8; ++j) {
        float4 av = ((const float4*)a)[j], dv = ((const float4*)d)[j];
        float2 f0 = __half22float2(hv[2*j]);
        float2 f1 = __half22float2(hv[2*j + 1]);
        ss += f0.x*av.x + f0.y*av.y + f1.x*av.z + f1.y*av.w;
        sd += f0.x*dv.x + f0.y*dv.y + f1.x*dv.z + f1.y*dv.w;
    }
    s_src[gid] = ss; s_dst[gid] = sd;
}

// ---------------- CSR build ----------------------------------------------
__global__ __launch_bounds__(256)
void zero_k(int* p, int n) { int i = blockIdx.x*256 + threadIdx.x; if (i < n) p[i] = 0; }

__global__ __launch_bounds__(256)
void count_k(const int* __restrict__ dst, int* __restrict__ counts) {
    int e = blockIdx.x*256 + threadIdx.x;
    if (e >= ET) return;
    int d = (e < N_EDG) ? dst[e] : (e - N_EDG);
    d = min(max(d, 0), N_NODES - 1);
    atomicAdd(&counts[d], 1);
}

// hierarchical scan: 1024-elem blocks (wave shuffle scan), then block offsets
__global__ __launch_bounds__(1024)
void scan1_k(int* __restrict__ counts, int* __restrict__ rowptr,
             int* __restrict__ blksum, int n) {
    __shared__ int wsum[16];
    const int tid = threadIdx.x, lane = tid & 63, wv = tid >> 6;
    const int i = blockIdx.x * 1024 + tid;
    int v = (i < n) ? counts[i] : 0;
    int s = v;
    #pragma unroll
    for (int off = 1; off < 64; off <<= 1) {
        int t = __shfl_up(s, off);
        if (lane >= off) s += t;
    }
    if (lane == 63) wsum[wv] = s;
    __syncthreads();
    if (wv == 0) {
        int ws = (lane < 16) ? wsum[lane] : 0;
        #pragma unroll
        for (int off = 1; off < 16; off <<= 1) {
            int t = __shfl_up(ws, off);
            if (lane >= off) ws += t;
        }
        if (lane < 16) wsum[lane] = ws;
    }
    __syncthreads();
    int excl = s - v + (wv > 0 ? wsum[wv - 1] : 0);
    if (i < n) { rowptr[i] = excl; counts[i] = excl; }
    if (tid == 0) blksum[blockIdx.x] = wsum[15];
}

__global__ __launch_bounds__(64)
void scan2_k(const int* __restrict__ blksum, int* __restrict__ blkoff, int nb) {
    int lane = threadIdx.x;
    int v = (lane < nb) ? blksum[lane] : 0;
    int s = v;
    #pragma unroll
    for (int off = 1; off < 64; off <<= 1) {
        int t = __shfl_up(s, off);
        if (lane >= off) s += t;
    }
    if (lane < nb) blkoff[lane] = s - v;
}

__global__ __launch_bounds__(256)
void scan3_k(int* __restrict__ rowptr, int* __restrict__ fillp,
             const int* __restrict__ blkoff, int n) {
    int i = blockIdx.x * 256 + threadIdx.x;
    if (i < n) {
        int off = blkoff[i >> 10];
        rowptr[i] += off;
        fillp[i]  += off;
    }
    if (i == 0) rowptr[n] = ET;
}

__global__ __launch_bounds__(256)
void fill_k(const int* __restrict__ src, const int* __restrict__ dst,
            int* __restrict__ fillptr, int* __restrict__ srcs) {
    int e = blockIdx.x*256 + threadIdx.x;
    if (e >= ET) return;
    int s, d;
    if (e < N_EDG) { s = src[e]; d = dst[e]; } else { s = e - N_EDG; d = s; }
    s = min(max(s, 0), N_NODES - 1);
    d = min(max(d, 0), N_NODES - 1);
    int pos = atomicAdd(&fillptr[d], 1);
    pos = min(max(pos, 0), ET - 1);
    srcs[pos] = s;
}

// ---------------- segment-softmax aggregation: one wave per dst node -----
// fp16 hp gather; pass 2 = 32 lanes x 2 edges, 16 B/lane loads.
// no max-subtraction: logits bounded (|e| <~ 3), softmax shift-invariant
__global__ __launch_bounds__(256)
void agg_k(const int* __restrict__ rowptr, const int* __restrict__ srcs,
           const float* __restrict__ s_src, const float* __restrict__ s_dst,
           const __half* __restrict__ hp, const float* __restrict__ bias,
           unsigned short* __restrict__ outhi, unsigned short* __restrict__ outlo,
           int out_off) {
    int wid  = (blockIdx.x * blockDim.x + threadIdx.x) >> 6;
    int lane = threadIdx.x & 63;
    if (wid >= N_NODES) return;
    const int n = wid;
    int r0 = rowptr[n], r1 = rowptr[n + 1];
    r0 = min(max(r0, 0), ET); r1 = min(max(r1, r0), ET);

    // pass 1: denominator. lane = slot*8 + h1 (8 edge-slots x 8 heads)
    const int h1 = lane & 7, slot = lane >> 3;
    const float sd1 = s_dst[n*NH + h1];
    float dn = 0.f;
    for (int i = r0 + slot; i < r1; i += 8) {
        int s = srcs[i];
        float ev = s_src[s*NH + h1] + sd1;
        ev = ev > 0.f ? ev : 0.2f * ev;
        dn += __expf(ev);
    }
    dn += __shfl_xor(dn, 8);
    dn += __shfl_xor(dn, 16);
    dn += __shfl_xor(dn, 32);
    // after reduction, lane h (h<8) holds dn for head h (h1 == lane&7)

    // pass 2: lane = eo*32 + sub. sub owns dims sub*8..sub*8+7 (head sub>>2);
    // eo in {0,1} picks edge parity; 16 B hp load per lane per edge.
    const int sub = lane & 31, eo = lane >> 5;
    const int h2  = sub >> 2;
    const float rdn = 1.f / __shfl(dn, h2);
    const float sd2 = __shfl(sd1, h2);   // lane h2 has h1==h2, sd1 == s_dst[n,h2]
    float a0=0.f,a1=0.f,a2=0.f,a3=0.f,a4=0.f,a5=0.f,a6=0.f,a7=0.f;
    for (int i = r0 + eo; i < r1; i += 2) {
        int s = srcs[i];
        float ev = s_src[s*NH + h2] + sd2;
        ev = ev > 0.f ? ev : 0.2f * ev;
        float ww = __expf(ev) * rdn;
        const __half2* hv = (const __half2*)(hp + (size_t)s * HID + sub * 8);
        __half2 p0 = hv[0], p1 = hv[1], p2 = hv[2], p3 = hv[3];   // one 16B load
        float2 f0 = __half22float2(p0), f1 = __half22float2(p1);
        float2 f2 = __half22float2(p2), f3 = __half22float2(p3);
        a0 += ww*f0.x; a1 += ww*f0.y; a2 += ww*f1.x; a3 += ww*f1.y;
        a4 += ww*f2.x; a5 += ww*f2.y; a6 += ww*f3.x; a7 += ww*f3.y;
    }
    // fold eo=1 into eo=0 (xor 32 swaps eo, keeps sub)
    a0 += __shfl_xor(a0, 32); a1 += __shfl_xor(a1, 32);
    a2 += __shfl_xor(a2, 32); a3 += __shfl_xor(a3, 32);
    a4 += __shfl_xor(a4, 32); a5 += __shfl_xor(a5, 32);
    a6 += __shfl_xor(a6, 32); a7 += __shfl_xor(a7, 32);
    if (lane < 32) {
        float v[8] = {a0,a1,a2,a3,a4,a5,a6,a7};
        const float4 b0 = *(const float4*)&bias[sub*8];
        const float4 b1 = *(const float4*)&bias[sub*8 + 4];
        v[0]+=b0.x; v[1]+=b0.y; v[2]+=b0.z; v[3]+=b0.w;
        v[4]+=b1.x; v[5]+=b1.y; v[6]+=b1.z; v[7]+=b1.w;
        unsigned short hh[8], ll[8];
        #pragma unroll
        for (int k = 0; k < 8; ++k) {
            float e = v[k] > 0.f ? v[k] : expm1f(v[k]);   // ELU
            hh[k] = f2bf(e); ll[k] = f2bf(e - bf2f(hh[k]));
        }
        size_t o = (size_t)n * 768 + out_off + sub * 8;
        *(uint4*)&outhi[o] = make_uint4(hh[0]|((unsigned)hh[1]<<16), hh[2]|((unsigned)hh[3]<<16),
                                        hh[4]|((unsigned)hh[5]<<16), hh[6]|((unsigned)hh[7]<<16));
        *(uint4*)&outlo[o] = make_uint4(ll[0]|((unsigned)ll[1]<<16), ll[2]|((unsigned)ll[3]<<16),
                                        ll[4]|((unsigned)ll[5]<<16), ll[6]|((unsigned)ll[7]<<16));
    }
}

// ---------------- semantic attention: scores -> softmax -> z -------------
__global__ __launch_bounds__(256)
void score_z_k(const float* t, const float* __restrict__ W2,
               const unsigned short* __restrict__ ehi,
               const unsigned short* __restrict__ elo,
               float* z) {
    int wid  = (blockIdx.x * blockDim.x + threadIdx.x) >> 6;
    int lane = threadIdx.x & 63;
    if (wid >= N_NODES) return;
    const int n = wid;
    float sc[3];
    #pragma unroll
    for (int p = 0; p < 3; ++p) {
        const float* tr = t + (size_t)(n*3 + p) * 128;
        float part = tr[lane] * W2[lane] + tr[64 + lane] * W2[64 + lane];
        #pragma unroll
        for (int o = 1; o < 64; o <<= 1) part += __shfl_xor(part, o);
        sc[p] = part;
    }
    float m  = fmaxf(sc[0], fmaxf(sc[1], sc[2]));
    float e0 = __expf(sc[0]-m), e1 = __expf(sc[1]-m), e2 = __expf(sc[2]-m);
    float rs = 1.f / (e0 + e1 + e2);
    e0 *= rs; e1 *= rs; e2 *= rs;
    const unsigned short* rh = ehi + (size_t)n * 768;
    const unsigned short* rl = elo + (size_t)n * 768;
    for (int c = lane; c < 256; c += 64) {
        float v0 = bf2f(rh[c])       + bf2f(rl[c]);
        float v1 = bf2f(rh[256 + c]) + bf2f(rl[256 + c]);
        float v2 = bf2f(rh[512 + c]) + bf2f(rl[512 + c]);
        z[(size_t)n*384 + c] = e0*v0 + e1*v1 + e2*v2;   // own row of t-arena
    }
}

__global__ __launch_bounds__(256)
void logits_k(const float* __restrict__ hcls, const float* __restrict__ W2,
              const float* __restrict__ b2, float* __restrict__ out) {
    int gid = blockIdx.x*256 + threadIdx.x;
    if (gid >= N_NODES * 2) return;
    int n = gid >> 1, o = gid & 1;
    const float* hr = hcls + (size_t)n * 128;
    float a = b2[o];
    #pragma unroll 4
    for (int j = 0; j < 128; ++j) a += hr[j] * W2[j*2 + o];
    out[gid] = a;
}

// -------------------------------------------------------------------------
extern "C" void kernel_launch(void* const* d_in, const int* in_sizes, int n_in,
                              void* d_out, int out_size, void* d_ws, size_t ws_size,
                              hipStream_t stream) {
    (void)in_sizes; (void)n_in; (void)out_size; (void)ws_size;
    const float* x     = (const float*)d_in[0];
    const int*   edges = (const int*)  d_in[1];
    const float* projW = (const float*)d_in[2];
    const float* projb = (const float*)d_in[3];
    const float* gatW  = (const float*)d_in[4];
    const float* gatAs = (const float*)d_in[5];
    const float* gatAd = (const float*)d_in[6];
    const float* gatB  = (const float*)d_in[7];
    const float* semW1 = (const float*)d_in[8];
    const float* semb1 = (const float*)d_in[9];
    const float* semW2 = (const float*)d_in[10];
    const float* clsW1 = (const float*)d_in[11];
    const float* clsb1 = (const float*)d_in[12];
    const float* clsW2 = (const float*)d_in[13];
    const float* clsb2 = (const float*)d_in[14];
    float* out = (float*)d_out;

    // ---- byte-addressed arena, high-water ~263.5 MB (same as passing R3) ----
    char* base = (char*)d_ws;
    const size_t PLANE = (size_t)N_NODES * HID * 2;      // 25.6 MB
    unsigned short* h0hi = (unsigned short*)(base);
    unsigned short* h0lo = (unsigned short*)(base + PLANE);
    __half*         hp16 = (__half*)(base + 2*PLANE);                 // 25.6 MB
    unsigned short* ehi  = (unsigned short*)(base + 4*PLANE);         // 76.8 MB
    unsigned short* elo  = (unsigned short*)(base + 7*PLANE);         // 76.8 MB
    char* small = base + 10*PLANE;
    float* ssrc = (float*)small;
    float* sdst = ssrc + (size_t)N_NODES*NH;
    int*   rowptr = (int*)(sdst + (size_t)N_NODES*NH);
    int*   fillp  = rowptr + (N_NODES + 2);
    int*   srcs   = fillp  + (N_NODES + 2);
    unsigned short* WThi = (unsigned short*)(srcs + ET);
    unsigned short* WTlo = WThi + 65536;
    int*   blksum = (int*)(WTlo + 65536);
    int*   blkoff = blksum + 64;
    // final-stage overlays (h0pair/hp16 dead):
    float* tbuf = (float*)base;                  // [N,3,128] f32 = [0, 3*PLANE)
    float* hcls = (float*)(base + 3*PLANE);      // [N,128] f32

    dim3 blk(256);
    const int gx = (N_NODES + 127) / 128;     // 391
    const int NB = (N_NODES + 1023) / 1024;   // 49 scan blocks

    // ---- projection: h0pair = split(x @ projW + projb), x f32 staged ----
    cvtW_k<<<(128*256 + 255)/256, blk, 0, stream>>>(projW, WThi, WTlo, 128, 256);
    mfma_gemm_k<256,0,1,1><<<dim3(gx,2), blk, 0, stream>>>(
        x, nullptr, nullptr, 128, WThi, WTlo, projb,
        nullptr, nullptr, h0hi, h0lo, 256, N_NODES, 128);

    for (int p = 0; p < 3; ++p) {
        const int* esrc = edges + (size_t)p * 2 * N_EDG;
        const int* edst = esrc + N_EDG;
        zero_k <<<(N_NODES+255)/256, blk, 0, stream>>>(fillp, N_NODES);
        count_k<<<(ET+255)/256,      blk, 0, stream>>>(edst, fillp);
        scan1_k<<<NB, 1024, 0, stream>>>(fillp, rowptr, blksum, N_NODES);
        scan2_k<<<1, 64, 0, stream>>>(blksum, blkoff, NB);
        scan3_k<<<(N_NODES+255)/256, blk, 0, stream>>>(rowptr, fillp, blkoff, N_NODES);
        fill_k <<<(ET+255)/256,      blk, 0, stream>>>(esrc, edst, fillp, srcs);

        for (int l = 0; l < 2; ++l) {
            const int pl = p*2 + l;
            cvtW_k<<<(256*256 + 255)/256, blk, 0, stream>>>(
                gatW + (size_t)pl * HID * HID, WThi, WTlo, 256, 256);
            const unsigned short* Ah = (l == 0) ? h0hi : ehi + p*HID;
            const unsigned short* Al = (l == 0) ? h0lo : elo + p*HID;
            const int lda = (l == 0) ? HID : 3*HID;
            mfma_gemm_k<256,0,2,0><<<dim3(gx,2), blk, 0, stream>>>(
                nullptr, Ah, Al, lda, WThi, WTlo, nullptr,
                nullptr, hp16, nullptr, nullptr, HID, N_NODES, HID);
            attn_scores_k<<<(N_NODES*NH+255)/256, blk, 0, stream>>>(
                hp16, gatAs + pl*HID, gatAd + pl*HID, ssrc, sdst);
            agg_k<<<(N_NODES*64)/256, blk, 0, stream>>>(
                rowptr, srcs, ssrc, sdst, hp16, gatB + pl*HID, ehi, elo, p*HID);
        }
    }

    // ---- semantic attention + classifier ----
    cvtW_k<<<(256*128 + 255)/256, blk, 0, stream>>>(semW1, WThi, WTlo, 256, 128);
    mfma_gemm_k<128,1,0,0><<<dim3((150000+127)/128, 1), blk, 0, stream>>>(
        nullptr, ehi, elo, 256, WThi, WTlo, semb1,
        tbuf, nullptr, nullptr, nullptr, 128, 150000, 256);
    score_z_k<<<(N_NODES*64)/256, blk, 0, stream>>>(tbuf, semW2, ehi, elo, tbuf);
    cvtW_k<<<(256*128 + 255)/256, blk, 0, stream>>>(clsW1, WThi, WTlo, 256, 128);
    mfma_gemm_k<128,2,0,1><<<dim3(gx, 1), blk, 0, stream>>>(
        tbuf, nullptr, nullptr, 384, WThi, WTlo, clsb1,
        hcls, nullptr, nullptr, nullptr, 128, N_NODES, 256);
    logits_k<<<(N_NODES*2+255)/256, blk, 0, stream>>>(hcls, clsW2, clsb2, out);
}

// Round 7
// 1465.638 us; speedup vs baseline: 2.5416x; 1.0069x over previous
//
#include <hip/hip_runtime.h>
#include <hip/hip_fp16.h>
#include <math.h>

#define N_NODES 50000
#define N_EDG   800000
#define ET      (N_EDG + N_NODES)   // +self loops
#define NH      8
#define DH      32
#define HID     256

typedef __attribute__((ext_vector_type(8))) short bf16x8;
typedef __attribute__((ext_vector_type(4))) float f32x4;

__device__ __forceinline__ unsigned short f2bf(float x) {
    unsigned u = __float_as_uint(x);
    u += 0x7FFF + ((u >> 16) & 1);          // RNE
    return (unsigned short)(u >> 16);
}
__device__ __forceinline__ float bf2f(unsigned short h) {
    return __uint_as_float(((unsigned)h) << 16);
}
__device__ __forceinline__ void split8(const float4& a, const float4& b,
                                       uint4& hi, uint4& lo) {
    float v[8] = {a.x,a.y,a.z,a.w,b.x,b.y,b.z,b.w};
    unsigned short h[8], l[8];
    #pragma unroll
    for (int i = 0; i < 8; ++i) { h[i] = f2bf(v[i]); l[i] = f2bf(v[i] - bf2f(h[i])); }
    hi = make_uint4(h[0]|((unsigned)h[1]<<16), h[2]|((unsigned)h[3]<<16),
                    h[4]|((unsigned)h[5]<<16), h[6]|((unsigned)h[7]<<16));
    lo = make_uint4(l[0]|((unsigned)l[1]<<16), l[2]|((unsigned)l[3]<<16),
                    l[4]|((unsigned)l[5]<<16), l[6]|((unsigned)l[7]<<16));
}
// async global->LDS, 16 B per lane; LDS dest = wave-uniform base + lane*16
__device__ __forceinline__ void gll16(const unsigned short* g, unsigned short* l) {
    __builtin_amdgcn_global_load_lds(
        (const __attribute__((address_space(1))) void*)g,
        (__attribute__((address_space(3))) void*)l, 16, 0, 0);
}

// ---------------- bf16x3 MFMA GEMM --------------------------------------
// C[M,NC] = act(A @ W + bias). A: bf16 hi/lo planes staged via
// global_load_lds (A32=0) or f32 split in-register (A32=1). W: transposed
// hi/lo planes WT[NC][K]. 128x128 tile, 256 thr, BK=32.
// LDS: 64 B/row unpadded, XOR-swizzled: phys16B = log16B ^ ((row>>2)&3)
// -> frag reads land 2 lanes/bank (free, m136); global_load_lds compatible.
// OUTMODE: 0 = f32 C, 1 = bf16 hi/lo planes, 2 = fp16
template<int NC, int ACT, int OUTMODE, int A32>
__global__ __launch_bounds__(256)
void mfma_gemm_k(const float* __restrict__ A32p,
                 const unsigned short* __restrict__ Ahi,
                 const unsigned short* __restrict__ Alo, int lda,
                 const unsigned short* __restrict__ WThi,
                 const unsigned short* __restrict__ WTlo,
                 const float* __restrict__ bias,
                 float* __restrict__ C, __half* __restrict__ Ch,
                 unsigned short* __restrict__ Chi, unsigned short* __restrict__ Clo,
                 int ldc, int M, int K) {
    __shared__ unsigned short sAh[128*32], sAl[128*32], sBh[128*32], sBl[128*32];
    const int tid  = threadIdx.x;
    const int lane = tid & 63;
    const int w    = tid >> 6;
    const int wr   = w >> 1, wc = w & 1;
    const int r0   = blockIdx.x * 128;
    const int c0   = blockIdx.y * 128;
    const int l15  = lane & 15, q = lane >> 4;

    // ---- staging geometry (global_load_lds): wave w stages rows
    // [w*32, w*32+32) of each plane as two 16-row / 1 KB chunks (j=0,1).
    // lane -> row w*32+j*16+(lane>>2), phys block lane&3;
    // swizzle for that row = ((lane>>2)>>2)&3 = (lane>>4)&3 (chunk base %16==0)
    const int cl8   = (((lane & 3) ^ ((lane >> 4) & 3)) << 3);  // logical col (shorts)
    const int lrow  = w*32 + (lane >> 2);
    int garow[2], gbrow[2];
    garow[0] = min(r0 + lrow,      M - 1);
    garow[1] = min(r0 + lrow + 16, M - 1);
    gbrow[0] = c0 + lrow;
    gbrow[1] = c0 + lrow + 16;
    const int lbase = w * 1024;               // shorts; +j*512

    // ---- A32 register-staging geometry (rows srow, srow+64)
    const int srow = tid >> 2, slot = tid & 3;
    const size_t ga0 = (size_t)min(r0 + srow,      M - 1) * lda + slot * 8;
    const size_t ga1 = (size_t)min(r0 + srow + 64, M - 1) * lda + slot * 8;
    const int lda0 = srow*32 + ((slot ^ ((srow >> 2) & 3)) << 3);
    const int lda1 = lda0 + 64*32;

    f32x4 acc[4][4];
    #pragma unroll
    for (int i = 0; i < 4; ++i)
        #pragma unroll
        for (int j = 0; j < 4; ++j) acc[i][j] = (f32x4){0.f, 0.f, 0.f, 0.f};

    const int swzF = (l15 >> 2) & 3;
    const int qs   = ((q ^ swzF) << 3);       // swizzled frag col offset (shorts)

    const int nsteps = K >> 5;
    for (int s = 0; s < nsteps; ++s) {
        const int kc = s << 5;
        __syncthreads();                       // prior step's frag reads done
        if constexpr (A32) {
            float4 f0a = *(const float4*)&A32p[ga0 + kc];
            float4 f0b = *(const float4*)&A32p[ga0 + kc + 4];
            float4 f1a = *(const float4*)&A32p[ga1 + kc];
            float4 f1b = *(const float4*)&A32p[ga1 + kc + 4];
            uint4 h0, l0, h1, l1;
            split8(f0a, f0b, h0, l0);
            split8(f1a, f1b, h1, l1);
            *(uint4*)&sAh[lda0] = h0; *(uint4*)&sAl[lda0] = l0;
            *(uint4*)&sAh[lda1] = h1; *(uint4*)&sAl[lda1] = l1;
        } else {
            #pragma unroll
            for (int j = 0; j < 2; ++j) {
                gll16(&Ahi[(size_t)garow[j]*lda + kc + cl8], &sAh[lbase + j*512]);
                gll16(&Alo[(size_t)garow[j]*lda + kc + cl8], &sAl[lbase + j*512]);
            }
        }
        #pragma unroll
        for (int j = 0; j < 2; ++j) {
            gll16(&WThi[(size_t)gbrow[j]*K + kc + cl8], &sBh[lbase + j*512]);
            gll16(&WTlo[(size_t)gbrow[j]*K + kc + cl8], &sBl[lbase + j*512]);
        }
        __syncthreads();                       // compiler drains vmcnt before barrier

        bf16x8 fAh[4], fAl[4];
        #pragma unroll
        for (int t = 0; t < 4; ++t) {
            int ra = (wr*64 + t*16 + l15) * 32 + qs;
            fAh[t] = *(const bf16x8*)&sAh[ra];
            fAl[t] = *(const bf16x8*)&sAl[ra];
        }
        #pragma unroll
        for (int nt = 0; nt < 4; ++nt) {
            int rb = (wc*64 + nt*16 + l15) * 32 + qs;
            bf16x8 fBh = *(const bf16x8*)&sBh[rb];
            bf16x8 fBl = *(const bf16x8*)&sBl[rb];
            #pragma unroll
            for (int mt = 0; mt < 4; ++mt) {
                acc[mt][nt] = __builtin_amdgcn_mfma_f32_16x16x32_bf16(fAh[mt], fBh, acc[mt][nt], 0, 0, 0);
                acc[mt][nt] = __builtin_amdgcn_mfma_f32_16x16x32_bf16(fAh[mt], fBl, acc[mt][nt], 0, 0, 0);
                acc[mt][nt] = __builtin_amdgcn_mfma_f32_16x16x32_bf16(fAl[mt], fBh, acc[mt][nt], 0, 0, 0);
            }
        }
    }
    // epilogue: C/D layout col=lane&15, row=(lane>>4)*4+reg  [m89-verified]
    #pragma unroll
    for (int mt = 0; mt < 4; ++mt)
        #pragma unroll
        for (int nt = 0; nt < 4; ++nt) {
            int col = c0 + wc*64 + nt*16 + l15;
            float bb = bias ? bias[col] : 0.f;
            #pragma unroll
            for (int r = 0; r < 4; ++r) {
                int grow = r0 + wr*64 + mt*16 + q*4 + r;
                if (grow < M) {
                    float v = acc[mt][nt][r] + bb;
                    if (ACT == 1) v = tanhf(v);
                    else if (ACT == 2) v = fmaxf(v, 0.f);
                    size_t o = (size_t)grow * ldc + col;
                    if (OUTMODE == 1) {
                        unsigned short h = f2bf(v);
                        Chi[o] = h;
                        Clo[o] = f2bf(v - bf2f(h));
                    } else if (OUTMODE == 2) {
                        Ch[o] = __float2half(v);
                    } else {
                        C[o] = v;
                    }
                }
            }
        }
}

// ---------------- batched weight transpose+split (all 9 weights) ---------
// slots: y=0..5 gatW[y] (256x256); y=6 projW (128x256); y=7 semW1 (256x128);
// y=8 clsW1 (256x128). WT buf: 9 slots x (65536 hi + 65536 lo) shorts.
__global__ __launch_bounds__(256)
void cvtWall_k(const float* __restrict__ gatW, const float* __restrict__ projW,
               const float* __restrict__ semW1, const float* __restrict__ clsW1,
               unsigned short* __restrict__ WT) {
    int y = blockIdx.y;
    const float* W; int K, N;
    if (y < 6)       { W = gatW + (size_t)y * 65536; K = 256; N = 256; }
    else if (y == 6) { W = projW; K = 128; N = 256; }
    else if (y == 7) { W = semW1; K = 256; N = 128; }
    else             { W = clsW1; K = 256; N = 128; }
    int idx = blockIdx.x * 256 + threadIdx.x;
    if (idx >= K * N) return;
    unsigned short* hi = WT + (size_t)y * 131072;
    unsigned short* lo = hi + 65536;
    int k = idx / N, n = idx - k * N;
    float v = W[idx];
    unsigned short h = f2bf(v);
    hi[n * K + k] = h;
    lo[n * K + k] = f2bf(v - bf2f(h));
}

// ---------------- per-(node,head) attention logits (fp16 hp) -------------
__global__ __launch_bounds__(256)
void attn_scores_k(const __half* __restrict__ hp, const float* __restrict__ a_src,
                   const float* __restrict__ a_dst,
                   float* __restrict__ s_src, float* __restrict__ s_dst) {
    int gid = blockIdx.x * 256 + threadIdx.x;     // (n,h)
    if (gid >= N_NODES * NH) return;
    int h = gid & 7;
    const __half2* hv = (const __half2*)(hp + (size_t)gid * DH);
    const float* a = a_src + h * DH;
    const float* d = a_dst + h * DH;
    float ss = 0.f, sd = 0.f;
    #pragma unroll
    for (int j = 0; j < 8; ++j) {
        float4 av = ((const float4*)a)[j], dv = ((const float4*)d)[j];
        float2 f0 = __half22float2(hv[2*j]);
        float2 f1 = __half22float2(hv[2*j + 1]);
        ss += f0.x*av.x + f0.y*av.y + f1.x*av.z + f1.y*av.w;
        sd += f0.x*dv.x + f0.y*dv.y + f1.x*dv.z + f1.y*dv.w;
    }
    s_src[gid] = ss; s_dst[gid] = sd;
}

// ---------------- CSR build (batched over 3 meta-paths) ------------------
__global__ __launch_bounds__(256)
void zero_k(int* p, int n) { int i = blockIdx.x*256 + threadIdx.x; if (i < n) p[i] = 0; }

__global__ __launch_bounds__(256)
void count3_k(const int* __restrict__ edges, int* __restrict__ counts3) {
    int e = blockIdx.x*256 + threadIdx.x;
    if (e >= 3*ET) return;
    int p = e / ET, i = e - p * ET;
    const int* dst = edges + (size_t)p * 2 * N_EDG + N_EDG;
    int d = (i < N_EDG) ? dst[i] : (i - N_EDG);
    d = min(max(d, 0), N_NODES - 1);
    atomicAdd(&counts3[p * N_NODES + d], 1);
}

// hierarchical scan per path: grid (NB, 3)
__global__ __launch_bounds__(1024)
void scan1_k(int* __restrict__ counts3, int* __restrict__ rowptr3,
             int* __restrict__ blksum3, int n) {
    __shared__ int wsum[16];
    const int p = blockIdx.y;
    int* counts = counts3 + p * n;
    int* rowptr = rowptr3 + p * (n + 1);
    const int tid = threadIdx.x, lane = tid & 63, wv = tid >> 6;
    const int i = blockIdx.x * 1024 + tid;
    int v = (i < n) ? counts[i] : 0;
    int s = v;
    #pragma unroll
    for (int off = 1; off < 64; off <<= 1) {
        int t = __shfl_up(s, off);
        if (lane >= off) s += t;
    }
    if (lane == 63) wsum[wv] = s;
    __syncthreads();
    if (wv == 0) {
        int ws = (lane < 16) ? wsum[lane] : 0;
        #pragma unroll
        for (int off = 1; off < 16; off <<= 1) {
            int t = __shfl_up(ws, off);
            if (lane >= off) ws += t;
        }
        if (lane < 16) wsum[lane] = ws;
    }
    __syncthreads();
    int excl = s - v + (wv > 0 ? wsum[wv - 1] : 0);
    if (i < n) { rowptr[i] = excl; counts[i] = excl; }
    if (tid == 0) blksum3[p * 64 + blockIdx.x] = wsum[15];
}

__global__ __launch_bounds__(64)
void scan2_k(const int* __restrict__ blksum3, int* __restrict__ blkoff3, int nb) {
    int p = blockIdx.x, lane = threadIdx.x;
    int v = (lane < nb) ? blksum3[p*64 + lane] : 0;
    int s = v;
    #pragma unroll
    for (int off = 1; off < 64; off <<= 1) {
        int t = __shfl_up(s, off);
        if (lane >= off) s += t;
    }
    if (lane < nb) blkoff3[p*64 + lane] = s - v;
}

__global__ __launch_bounds__(256)
void scan3_k(int* __restrict__ rowptr3, int* __restrict__ fillp3,
             const int* __restrict__ blkoff3, int n) {
    int p = blockIdx.y;
    int i = blockIdx.x * 256 + threadIdx.x;
    if (i < n) {
        int off = blkoff3[p*64 + (i >> 10)];
        rowptr3[p*(n+1) + i] += off;
        fillp3[p*n + i]      += off;
    }
    if (i == 0) rowptr3[p*(n+1) + n] = ET;
}

__global__ __launch_bounds__(256)
void fill3_k(const int* __restrict__ edges, int* __restrict__ fillp3,
             int* __restrict__ srcs3) {
    int e = blockIdx.x*256 + threadIdx.x;
    if (e >= 3*ET) return;
    int p = e / ET, i = e - p * ET;
    const int* src = edges + (size_t)p * 2 * N_EDG;
    const int* dst = src + N_EDG;
    int s, d;
    if (i < N_EDG) { s = src[i]; d = dst[i]; } else { s = i - N_EDG; d = s; }
    s = min(max(s, 0), N_NODES - 1);
    d = min(max(d, 0), N_NODES - 1);
    int pos = atomicAdd(&fillp3[p * N_NODES + d], 1);
    pos = min(max(pos, 0), ET - 1);
    srcs3[(size_t)p * ET + pos] = s;
}

// ---------------- segment-softmax aggregation: one wave per dst node -----
// fp16 hp gather; pass 2 = 32 lanes x 2 edges, 16 B/lane loads.
// no max-subtraction: logits bounded (|e| <~ 3), softmax shift-invariant
__global__ __launch_bounds__(256)
void agg_k(const int* __restrict__ rowptr, const int* __restrict__ srcs,
           const float* __restrict__ s_src, const float* __restrict__ s_dst,
           const __half* __restrict__ hp, const float* __restrict__ bias,
           unsigned short* __restrict__ outhi, unsigned short* __restrict__ outlo,
           int out_off) {
    int wid  = (blockIdx.x * blockDim.x + threadIdx.x) >> 6;
    int lane = threadIdx.x & 63;
    if (wid >= N_NODES) return;
    const int n = wid;
    int r0 = rowptr[n], r1 = rowptr[n + 1];
    r0 = min(max(r0, 0), ET); r1 = min(max(r1, r0), ET);

    // pass 1: denominator. lane = slot*8 + h1 (8 edge-slots x 8 heads)
    const int h1 = lane & 7, slot = lane >> 3;
    const float sd1 = s_dst[n*NH + h1];
    float dn = 0.f;
    for (int i = r0 + slot; i < r1; i += 8) {
        int s = srcs[i];
        float ev = s_src[s*NH + h1] + sd1;
        ev = ev > 0.f ? ev : 0.2f * ev;
        dn += __expf(ev);
    }
    dn += __shfl_xor(dn, 8);
    dn += __shfl_xor(dn, 16);
    dn += __shfl_xor(dn, 32);
    // after reduction, lane h (h<8) holds dn for head h

    // pass 2: lane = eo*32 + sub. sub owns dims sub*8..sub*8+7 (head sub>>2);
    // eo picks edge parity; one 16 B hp load per lane per edge.
    const int sub = lane & 31, eo = lane >> 5;
    const int h2  = sub >> 2;
    const float rdn = 1.f / __shfl(dn, h2);
    const float sd2 = __shfl(sd1, h2);
    float a0=0.f,a1=0.f,a2=0.f,a3=0.f,a4=0.f,a5=0.f,a6=0.f,a7=0.f;
    for (int i = r0 + eo; i < r1; i += 2) {
        int s = srcs[i];
        float ev = s_src[s*NH + h2] + sd2;
        ev = ev > 0.f ? ev : 0.2f * ev;
        float ww = __expf(ev) * rdn;
        const __half2* hv = (const __half2*)(hp + (size_t)s * HID + sub * 8);
        __half2 p0 = hv[0], p1 = hv[1], p2 = hv[2], p3 = hv[3];   // one 16B load
        float2 f0 = __half22float2(p0), f1 = __half22float2(p1);
        float2 f2 = __half22float2(p2), f3 = __half22float2(p3);
        a0 += ww*f0.x; a1 += ww*f0.y; a2 += ww*f1.x; a3 += ww*f1.y;
        a4 += ww*f2.x; a5 += ww*f2.y; a6 += ww*f3.x; a7 += ww*f3.y;
    }
    a0 += __shfl_xor(a0, 32); a1 += __shfl_xor(a1, 32);
    a2 += __shfl_xor(a2, 32); a3 += __shfl_xor(a3, 32);
    a4 += __shfl_xor(a4, 32); a5 += __shfl_xor(a5, 32);
    a6 += __shfl_xor(a6, 32); a7 += __shfl_xor(a7, 32);
    if (lane < 32) {
        float v[8] = {a0,a1,a2,a3,a4,a5,a6,a7};
        const float4 b0 = *(const float4*)&bias[sub*8];
        const float4 b1 = *(const float4*)&bias[sub*8 + 4];
        v[0]+=b0.x; v[1]+=b0.y; v[2]+=b0.z; v[3]+=b0.w;
        v[4]+=b1.x; v[5]+=b1.y; v[6]+=b1.z; v[7]+=b1.w;
        unsigned short hh[8], ll[8];
        #pragma unroll
        for (int k = 0; k < 8; ++k) {
            float e = v[k] > 0.f ? v[k] : expm1f(v[k]);   // ELU
            hh[k] = f2bf(e); ll[k] = f2bf(e - bf2f(hh[k]));
        }
        size_t o = (size_t)n * 768 + out_off + sub * 8;
        *(uint4*)&outhi[o] = make_uint4(hh[0]|((unsigned)hh[1]<<16), hh[2]|((unsigned)hh[3]<<16),
                                        hh[4]|((unsigned)hh[5]<<16), hh[6]|((unsigned)hh[7]<<16));
        *(uint4*)&outlo[o] = make_uint4(ll[0]|((unsigned)ll[1]<<16), ll[2]|((unsigned)ll[3]<<16),
                                        ll[4]|((unsigned)ll[5]<<16), ll[6]|((unsigned)ll[7]<<16));
    }
}

// ---------------- semantic attention: scores -> softmax -> z -------------
__global__ __launch_bounds__(256)
void score_z_k(const float* t, const float* __restrict__ W2,
               const unsigned short* __restrict__ ehi,
               const unsigned short* __restrict__ elo,
               float* z) {
    int wid  = (blockIdx.x * blockDim.x + threadIdx.x) >> 6;
    int lane = threadIdx.x & 63;
    if (wid >= N_NODES) return;
    const int n = wid;
    float sc[3];
    #pragma unroll
    for (int p = 0; p < 3; ++p) {
        const float* tr = t + (size_t)(n*3 + p) * 128;
        float part = tr[lane] * W2[lane] + tr[64 + lane] * W2[64 + lane];
        #pragma unroll
        for (int o = 1; o < 64; o <<= 1) part += __shfl_xor(part, o);
        sc[p] = part;
    }
    float m  = fmaxf(sc[0], fmaxf(sc[1], sc[2]));
    float e0 = __expf(sc[0]-m), e1 = __expf(sc[1]-m), e2 = __expf(sc[2]-m);
    float rs = 1.f / (e0 + e1 + e2);
    e0 *= rs; e1 *= rs; e2 *= rs;
    const unsigned short* rh = ehi + (size_t)n * 768;
    const unsigned short* rl = elo + (size_t)n * 768;
    for (int c = lane; c < 256; c += 64) {
        float v0 = bf2f(rh[c])       + bf2f(rl[c]);
        float v1 = bf2f(rh[256 + c]) + bf2f(rl[256 + c]);
        float v2 = bf2f(rh[512 + c]) + bf2f(rl[512 + c]);
        z[(size_t)n*384 + c] = e0*v0 + e1*v1 + e2*v2;   // own row of t-arena
    }
}

__global__ __launch_bounds__(256)
void logits_k(const float* __restrict__ hcls, const float* __restrict__ W2,
              const float* __restrict__ b2, float* __restrict__ out) {
    int gid = blockIdx.x*256 + threadIdx.x;
    if (gid >= N_NODES * 2) return;
    int n = gid >> 1, o = gid & 1;
    const float* hr = hcls + (size_t)n * 128;
    float a = b2[o];
    #pragma unroll 4
    for (int j = 0; j < 128; ++j) a += hr[j] * W2[j*2 + o];
    out[gid] = a;
}

// -------------------------------------------------------------------------
extern "C" void kernel_launch(void* const* d_in, const int* in_sizes, int n_in,
                              void* d_out, int out_size, void* d_ws, size_t ws_size,
                              hipStream_t stream) {
    (void)in_sizes; (void)n_in; (void)out_size; (void)ws_size;
    const float* x     = (const float*)d_in[0];
    const int*   edges = (const int*)  d_in[1];
    const float* projW = (const float*)d_in[2];
    const float* projb = (const float*)d_in[3];
    const float* gatW  = (const float*)d_in[4];
    const float* gatAs = (const float*)d_in[5];
    const float* gatAd = (const float*)d_in[6];
    const float* gatB  = (const float*)d_in[7];
    const float* semW1 = (const float*)d_in[8];
    const float* semb1 = (const float*)d_in[9];
    const float* semW2 = (const float*)d_in[10];
    const float* clsW1 = (const float*)d_in[11];
    const float* clsb1 = (const float*)d_in[12];
    const float* clsW2 = (const float*)d_in[13];
    const float* clsb2 = (const float*)d_in[14];
    float* out = (float*)d_out;

    // ---- byte-addressed arena, high-water ~263 MB ----
    char* base = (char*)d_ws;
    const size_t PLANE = (size_t)N_NODES * HID * 2;      // 25.6 MB
    unsigned short* h0hi = (unsigned short*)(base);
    unsigned short* h0lo = (unsigned short*)(base + PLANE);
    __half*         hp16 = (__half*)(base + 2*PLANE);                 // 25.6 MB
    int*            srcs3 = (int*)(base + 3*PLANE);                   // 10.2 MB (gap)
    unsigned short* ehi  = (unsigned short*)(base + 4*PLANE);         // 76.8 MB
    unsigned short* elo  = (unsigned short*)(base + 7*PLANE);         // 76.8 MB
    char* small = base + 10*PLANE;                                    // at 256 MB
    float* ssrc = (float*)small;
    float* sdst = ssrc + (size_t)N_NODES*NH;
    int*   rowptr3 = (int*)(sdst + (size_t)N_NODES*NH);  // 3*(N+1)
    int*   fillp3  = rowptr3 + 3*(N_NODES + 1);          // 3*N
    int*   blksum3 = fillp3 + 3*N_NODES;                 // 3*64
    int*   blkoff3 = blksum3 + 192;                      // 3*64
    unsigned short* WT = (unsigned short*)(blkoff3 + 192); // 9*131072 shorts
    // final-stage overlays (h0pair/hp16/srcs3 dead):
    float* tbuf = (float*)base;                  // [N,3,128] f32 = [0, 3*PLANE)
    float* hcls = (float*)(base + 3*PLANE);      // [N,128] f32

    dim3 blk(256);
    const int gx = (N_NODES + 127) / 128;     // 391
    const int NB = (N_NODES + 1023) / 1024;   // 49 scan blocks/path

    // ---- all weight transposes in one dispatch ----
    cvtWall_k<<<dim3(256, 9), blk, 0, stream>>>(gatW, projW, semW1, clsW1, WT);

    // ---- CSR build, all 3 meta-paths batched ----
    zero_k  <<<(3*N_NODES+255)/256, blk, 0, stream>>>(fillp3, 3*N_NODES);
    count3_k<<<(3*ET+255)/256,      blk, 0, stream>>>(edges, fillp3);
    scan1_k <<<dim3(NB,3), 1024, 0, stream>>>(fillp3, rowptr3, blksum3, N_NODES);
    scan2_k <<<3, 64, 0, stream>>>(blksum3, blkoff3, NB);
    scan3_k <<<dim3((N_NODES+255)/256,3), blk, 0, stream>>>(rowptr3, fillp3, blkoff3, N_NODES);
    fill3_k <<<(3*ET+255)/256,      blk, 0, stream>>>(edges, fillp3, srcs3);

    // ---- projection: h0pair = split(x @ projW + projb), x f32 staged ----
    mfma_gemm_k<256,0,1,1><<<dim3(gx,2), blk, 0, stream>>>(
        x, nullptr, nullptr, 128, WT + 6*131072, WT + 6*131072 + 65536, projb,
        nullptr, nullptr, h0hi, h0lo, 256, N_NODES, 128);

    for (int p = 0; p < 3; ++p) {
        for (int l = 0; l < 2; ++l) {
            const int pl = p*2 + l;
            const unsigned short* Ah = (l == 0) ? h0hi : ehi + p*HID;
            const unsigned short* Al = (l == 0) ? h0lo : elo + p*HID;
            const int lda = (l == 0) ? HID : 3*HID;
            mfma_gemm_k<256,0,2,0><<<dim3(gx,2), blk, 0, stream>>>(
                nullptr, Ah, Al, lda, WT + (size_t)pl*131072, WT + (size_t)pl*131072 + 65536,
                nullptr, nullptr, hp16, nullptr, nullptr, HID, N_NODES, HID);
            attn_scores_k<<<(N_NODES*NH+255)/256, blk, 0, stream>>>(
                hp16, gatAs + pl*HID, gatAd + pl*HID, ssrc, sdst);
            agg_k<<<(N_NODES*64)/256, blk, 0, stream>>>(
                rowptr3 + p*(N_NODES+1), srcs3 + (size_t)p*ET, ssrc, sdst,
                hp16, gatB + pl*HID, ehi, elo, p*HID);
        }
    }

    // ---- semantic attention + classifier ----
    mfma_gemm_k<128,1,0,0><<<dim3((150000+127)/128, 1), blk, 0, stream>>>(
        nullptr, ehi, elo, 256, WT + 7*131072, WT + 7*131072 + 65536, semb1,
        tbuf, nullptr, nullptr, nullptr, 128, 150000, 256);
    score_z_k<<<(N_NODES*64)/256, blk, 0, stream>>>(tbuf, semW2, ehi, elo, tbuf);
    mfma_gemm_k<128,2,0,1><<<dim3(gx, 1), blk, 0, stream>>>(
        tbuf, nullptr, nullptr, 384, WT + 8*131072, WT + 8*131072 + 65536, clsb1,
        hcls, nullptr, nullptr, nullptr, 128, N_NODES, 256);
    logits_k<<<(N_NODES*2+255)/256, blk, 0, stream>>>(hcls, clsW2, clsb2, out);
}

// Round 8
// 1281.916 us; speedup vs baseline: 2.9059x; 1.1433x over previous
//
#include <hip/hip_runtime.h>
#include <hip/hip_fp16.h>
#include <math.h>

#define N_NODES 50000
#define N_EDG   800000
#define ET      (N_EDG + N_NODES)   // +self loops
#define NH      8
#define DH      32
#define HID     256

typedef __attribute__((ext_vector_type(8))) short bf16x8;
typedef __attribute__((ext_vector_type(4))) float f32x4;

__device__ __forceinline__ unsigned short f2bf(float x) {
    unsigned u = __float_as_uint(x);
    u += 0x7FFF + ((u >> 16) & 1);          // RNE
    return (unsigned short)(u >> 16);
}
__device__ __forceinline__ float bf2f(unsigned short h) {
    return __uint_as_float(((unsigned)h) << 16);
}
__device__ __forceinline__ void split8(const float4& a, const float4& b,
                                       uint4& hi, uint4& lo) {
    float v[8] = {a.x,a.y,a.z,a.w,b.x,b.y,b.z,b.w};
    unsigned short h[8], l[8];
    #pragma unroll
    for (int i = 0; i < 8; ++i) { h[i] = f2bf(v[i]); l[i] = f2bf(v[i] - bf2f(h[i])); }
    hi = make_uint4(h[0]|((unsigned)h[1]<<16), h[2]|((unsigned)h[3]<<16),
                    h[4]|((unsigned)h[5]<<16), h[6]|((unsigned)h[7]<<16));
    lo = make_uint4(l[0]|((unsigned)l[1]<<16), l[2]|((unsigned)l[3]<<16),
                    l[4]|((unsigned)l[5]<<16), l[6]|((unsigned)l[7]<<16));
}
// async global->LDS, 16 B per lane; LDS dest = wave-uniform base + lane*16
__device__ __forceinline__ void gll16(const unsigned short* g, unsigned short* l) {
    __builtin_amdgcn_global_load_lds(
        (const __attribute__((address_space(1))) void*)g,
        (__attribute__((address_space(3))) void*)l, 16, 0, 0);
}

// ================= bf16x3 MFMA GEMM, single (proj/sem/cls) ===============
// LDS: 64 B/row unpadded, XOR-swizzled: phys16B = log16B ^ ((row>>2)&3)
// OUTMODE: 0 = f32 C, 1 = bf16 hi/lo planes.  A32: f32 A split in-register.
template<int NC, int ACT, int OUTMODE, int A32>
__global__ __launch_bounds__(256)
void mfma_gemm_k(const float* __restrict__ A32p,
                 const unsigned short* __restrict__ Ahi,
                 const unsigned short* __restrict__ Alo, int lda,
                 const unsigned short* __restrict__ WThi,
                 const unsigned short* __restrict__ WTlo,
                 const float* __restrict__ bias,
                 float* __restrict__ C,
                 unsigned short* __restrict__ Chi, unsigned short* __restrict__ Clo,
                 int ldc, int M, int K) {
    __shared__ unsigned short sAh[128*32], sAl[128*32], sBh[128*32], sBl[128*32];
    const int tid  = threadIdx.x;
    const int lane = tid & 63;
    const int w    = tid >> 6;
    const int wr   = w >> 1, wc = w & 1;
    const int r0   = blockIdx.x * 128;
    const int c0   = blockIdx.y * 128;
    const int l15  = lane & 15, q = lane >> 4;

    const int cl8   = (((lane & 3) ^ ((lane >> 4) & 3)) << 3);
    const int lrow  = w*32 + (lane >> 2);
    int garow[2], gbrow[2];
    garow[0] = min(r0 + lrow,      M - 1);
    garow[1] = min(r0 + lrow + 16, M - 1);
    gbrow[0] = c0 + lrow;
    gbrow[1] = c0 + lrow + 16;
    const int lbase = w * 1024;

    const int srow = tid >> 2, slot = tid & 3;
    const size_t ga0 = (size_t)min(r0 + srow,      M - 1) * lda + slot * 8;
    const size_t ga1 = (size_t)min(r0 + srow + 64, M - 1) * lda + slot * 8;
    const int lda0 = srow*32 + ((slot ^ ((srow >> 2) & 3)) << 3);
    const int lda1 = lda0 + 64*32;

    f32x4 acc[4][4];
    #pragma unroll
    for (int i = 0; i < 4; ++i)
        #pragma unroll
        for (int j = 0; j < 4; ++j) acc[i][j] = (f32x4){0.f, 0.f, 0.f, 0.f};

    const int swzF = (l15 >> 2) & 3;
    const int qs   = ((q ^ swzF) << 3);

    const int nsteps = K >> 5;
    for (int s = 0; s < nsteps; ++s) {
        const int kc = s << 5;
        __syncthreads();
        if constexpr (A32) {
            float4 f0a = *(const float4*)&A32p[ga0 + kc];
            float4 f0b = *(const float4*)&A32p[ga0 + kc + 4];
            float4 f1a = *(const float4*)&A32p[ga1 + kc];
            float4 f1b = *(const float4*)&A32p[ga1 + kc + 4];
            uint4 h0, l0, h1, l1;
            split8(f0a, f0b, h0, l0);
            split8(f1a, f1b, h1, l1);
            *(uint4*)&sAh[lda0] = h0; *(uint4*)&sAl[lda0] = l0;
            *(uint4*)&sAh[lda1] = h1; *(uint4*)&sAl[lda1] = l1;
        } else {
            #pragma unroll
            for (int j = 0; j < 2; ++j) {
                gll16(&Ahi[(size_t)garow[j]*lda + kc + cl8], &sAh[lbase + j*512]);
                gll16(&Alo[(size_t)garow[j]*lda + kc + cl8], &sAl[lbase + j*512]);
            }
        }
        #pragma unroll
        for (int j = 0; j < 2; ++j) {
            gll16(&WThi[(size_t)gbrow[j]*K + kc + cl8], &sBh[lbase + j*512]);
            gll16(&WTlo[(size_t)gbrow[j]*K + kc + cl8], &sBl[lbase + j*512]);
        }
        __syncthreads();

        bf16x8 fAh[4], fAl[4];
        #pragma unroll
        for (int t = 0; t < 4; ++t) {
            int ra = (wr*64 + t*16 + l15) * 32 + qs;
            fAh[t] = *(const bf16x8*)&sAh[ra];
            fAl[t] = *(const bf16x8*)&sAl[ra];
        }
        #pragma unroll
        for (int nt = 0; nt < 4; ++nt) {
            int rb = (wc*64 + nt*16 + l15) * 32 + qs;
            bf16x8 fBh = *(const bf16x8*)&sBh[rb];
            bf16x8 fBl = *(const bf16x8*)&sBl[rb];
            #pragma unroll
            for (int mt = 0; mt < 4; ++mt) {
                acc[mt][nt] = __builtin_amdgcn_mfma_f32_16x16x32_bf16(fAh[mt], fBh, acc[mt][nt], 0, 0, 0);
                acc[mt][nt] = __builtin_amdgcn_mfma_f32_16x16x32_bf16(fAh[mt], fBl, acc[mt][nt], 0, 0, 0);
                acc[mt][nt] = __builtin_amdgcn_mfma_f32_16x16x32_bf16(fAl[mt], fBh, acc[mt][nt], 0, 0, 0);
            }
        }
    }
    // epilogue: C/D layout col=lane&15, row=(lane>>4)*4+reg  [m89-verified]
    #pragma unroll
    for (int mt = 0; mt < 4; ++mt)
        #pragma unroll
        for (int nt = 0; nt < 4; ++nt) {
            int col = c0 + wc*64 + nt*16 + l15;
            float bb = bias ? bias[col] : 0.f;
            #pragma unroll
            for (int r = 0; r < 4; ++r) {
                int grow = r0 + wr*64 + mt*16 + q*4 + r;
                if (grow < M) {
                    float v = acc[mt][nt][r] + bb;
                    if (ACT == 1) v = tanhf(v);
                    else if (ACT == 2) v = fmaxf(v, 0.f);
                    size_t o = (size_t)grow * ldc + col;
                    if (OUTMODE == 1) {
                        unsigned short h = f2bf(v);
                        Chi[o] = h;
                        Clo[o] = f2bf(v - bf2f(h));
                    } else {
                        C[o] = v;
                    }
                }
            }
        }
}

// ================= bf16x3 MFMA GEMM, 3 meta-paths batched ================
// blockIdx.z = path p. A = Ahi/Alo + p*aoffz (shorts), W slot = 2p+l,
// out fp16 hp3 + p*N*HID. No bias/act.
__global__ __launch_bounds__(256)
void mfma_gemm3_k(const unsigned short* __restrict__ Ahi,
                  const unsigned short* __restrict__ Alo,
                  int aoffz, int lda,
                  const unsigned short* __restrict__ WT, int l,
                  __half* __restrict__ hp3, int M) {
    __shared__ unsigned short sAh[128*32], sAl[128*32], sBh[128*32], sBl[128*32];
    const int p = blockIdx.z;
    Ahi += (size_t)p * aoffz;
    Alo += (size_t)p * aoffz;
    const unsigned short* WThi = WT + (size_t)(2*p + l) * 131072;
    const unsigned short* WTlo = WThi + 65536;
    __half* Ch = hp3 + (size_t)p * N_NODES * HID;
    const int K = HID;

    const int tid  = threadIdx.x;
    const int lane = tid & 63;
    const int w    = tid >> 6;
    const int wr   = w >> 1, wc = w & 1;
    const int r0   = blockIdx.x * 128;
    const int c0   = blockIdx.y * 128;
    const int l15  = lane & 15, q = lane >> 4;

    const int cl8   = (((lane & 3) ^ ((lane >> 4) & 3)) << 3);
    const int lrow  = w*32 + (lane >> 2);
    int garow[2], gbrow[2];
    garow[0] = min(r0 + lrow,      M - 1);
    garow[1] = min(r0 + lrow + 16, M - 1);
    gbrow[0] = c0 + lrow;
    gbrow[1] = c0 + lrow + 16;
    const int lbase = w * 1024;

    f32x4 acc[4][4];
    #pragma unroll
    for (int i = 0; i < 4; ++i)
        #pragma unroll
        for (int j = 0; j < 4; ++j) acc[i][j] = (f32x4){0.f, 0.f, 0.f, 0.f};

    const int swzF = (l15 >> 2) & 3;
    const int qs   = ((q ^ swzF) << 3);

    for (int s = 0; s < 8; ++s) {             // K=256, BK=32
        const int kc = s << 5;
        __syncthreads();
        #pragma unroll
        for (int j = 0; j < 2; ++j) {
            gll16(&Ahi[(size_t)garow[j]*lda + kc + cl8], &sAh[lbase + j*512]);
            gll16(&Alo[(size_t)garow[j]*lda + kc + cl8], &sAl[lbase + j*512]);
            gll16(&WThi[(size_t)gbrow[j]*K + kc + cl8], &sBh[lbase + j*512]);
            gll16(&WTlo[(size_t)gbrow[j]*K + kc + cl8], &sBl[lbase + j*512]);
        }
        __syncthreads();

        bf16x8 fAh[4], fAl[4];
        #pragma unroll
        for (int t = 0; t < 4; ++t) {
            int ra = (wr*64 + t*16 + l15) * 32 + qs;
            fAh[t] = *(const bf16x8*)&sAh[ra];
            fAl[t] = *(const bf16x8*)&sAl[ra];
        }
        #pragma unroll
        for (int nt = 0; nt < 4; ++nt) {
            int rb = (wc*64 + nt*16 + l15) * 32 + qs;
            bf16x8 fBh = *(const bf16x8*)&sBh[rb];
            bf16x8 fBl = *(const bf16x8*)&sBl[rb];
            #pragma unroll
            for (int mt = 0; mt < 4; ++mt) {
                acc[mt][nt] = __builtin_amdgcn_mfma_f32_16x16x32_bf16(fAh[mt], fBh, acc[mt][nt], 0, 0, 0);
                acc[mt][nt] = __builtin_amdgcn_mfma_f32_16x16x32_bf16(fAh[mt], fBl, acc[mt][nt], 0, 0, 0);
                acc[mt][nt] = __builtin_amdgcn_mfma_f32_16x16x32_bf16(fAl[mt], fBh, acc[mt][nt], 0, 0, 0);
            }
        }
    }
    #pragma unroll
    for (int mt = 0; mt < 4; ++mt)
        #pragma unroll
        for (int nt = 0; nt < 4; ++nt) {
            int col = c0 + wc*64 + nt*16 + l15;
            #pragma unroll
            for (int r = 0; r < 4; ++r) {
                int grow = r0 + wr*64 + mt*16 + q*4 + r;
                if (grow < M)
                    Ch[(size_t)grow * HID + col] = __float2half(acc[mt][nt][r]);
            }
        }
}

// ---------------- batched weight transpose+split (all 9 weights) ---------
__global__ __launch_bounds__(256)
void cvtWall_k(const float* __restrict__ gatW, const float* __restrict__ projW,
               const float* __restrict__ semW1, const float* __restrict__ clsW1,
               unsigned short* __restrict__ WT) {
    int y = blockIdx.y;
    const float* W; int K, N;
    if (y < 6)       { W = gatW + (size_t)y * 65536; K = 256; N = 256; }
    else if (y == 6) { W = projW; K = 128; N = 256; }
    else if (y == 7) { W = semW1; K = 256; N = 128; }
    else             { W = clsW1; K = 256; N = 128; }
    int idx = blockIdx.x * 256 + threadIdx.x;
    if (idx >= K * N) return;
    unsigned short* hi = WT + (size_t)y * 131072;
    unsigned short* lo = hi + 65536;
    int k = idx / N, n = idx - k * N;
    float v = W[idx];
    unsigned short h = f2bf(v);
    hi[n * K + k] = h;
    lo[n * K + k] = f2bf(v - bf2f(h));
}

// ---------------- attention logits, 3 paths batched ----------------------
__global__ __launch_bounds__(256)
void attn_scores3_k(const __half* __restrict__ hp3,
                    const float* __restrict__ gatAs, const float* __restrict__ gatAd,
                    int l, float* __restrict__ ssrc3, float* __restrict__ sdst3) {
    int p = blockIdx.y;
    int gid = blockIdx.x * 256 + threadIdx.x;     // (n,h) within path
    if (gid >= N_NODES * NH) return;
    int h = gid & 7;
    const __half2* hv = (const __half2*)(hp3 + (size_t)p * N_NODES * HID + (size_t)gid * DH);
    const float* a = gatAs + (2*p + l) * HID + h * DH;
    const float* d = gatAd + (2*p + l) * HID + h * DH;
    float ss = 0.f, sd = 0.f;
    #pragma unroll
    for (int j = 0; j < 8; ++j) {
        float4 av = ((const float4*)a)[j], dv = ((const float4*)d)[j];
        float2 f0 = __half22float2(hv[2*j]);
        float2 f1 = __half22float2(hv[2*j + 1]);
        ss += f0.x*av.x + f0.y*av.y + f1.x*av.z + f1.y*av.w;
        sd += f0.x*dv.x + f0.y*dv.y + f1.x*dv.z + f1.y*dv.w;
    }
    ssrc3[p * N_NODES * NH + gid] = ss;
    sdst3[p * N_NODES * NH + gid] = sd;
}

// ---------------- CSR build (batched over 3 meta-paths) ------------------
__global__ __launch_bounds__(256)
void zero_k(int* p, int n) { int i = blockIdx.x*256 + threadIdx.x; if (i < n) p[i] = 0; }

__global__ __launch_bounds__(256)
void count3_k(const int* __restrict__ edges, int* __restrict__ counts3) {
    int e = blockIdx.x*256 + threadIdx.x;
    if (e >= 3*ET) return;
    int p = e / ET, i = e - p * ET;
    const int* dst = edges + (size_t)p * 2 * N_EDG + N_EDG;
    int d = (i < N_EDG) ? dst[i] : (i - N_EDG);
    d = min(max(d, 0), N_NODES - 1);
    atomicAdd(&counts3[p * N_NODES + d], 1);
}

__global__ __launch_bounds__(1024)
void scan1_k(int* __restrict__ counts3, int* __restrict__ rowptr3,
             int* __restrict__ blksum3, int n) {
    __shared__ int wsum[16];
    const int p = blockIdx.y;
    int* counts = counts3 + p * n;
    int* rowptr = rowptr3 + p * (n + 1);
    const int tid = threadIdx.x, lane = tid & 63, wv = tid >> 6;
    const int i = blockIdx.x * 1024 + tid;
    int v = (i < n) ? counts[i] : 0;
    int s = v;
    #pragma unroll
    for (int off = 1; off < 64; off <<= 1) {
        int t = __shfl_up(s, off);
        if (lane >= off) s += t;
    }
    if (lane == 63) wsum[wv] = s;
    __syncthreads();
    if (wv == 0) {
        int ws = (lane < 16) ? wsum[lane] : 0;
        #pragma unroll
        for (int off = 1; off < 16; off <<= 1) {
            int t = __shfl_up(ws, off);
            if (lane >= off) ws += t;
        }
        if (lane < 16) wsum[lane] = ws;
    }
    __syncthreads();
    int excl = s - v + (wv > 0 ? wsum[wv - 1] : 0);
    if (i < n) { rowptr[i] = excl; counts[i] = excl; }
    if (tid == 0) blksum3[p * 64 + blockIdx.x] = wsum[15];
}

__global__ __launch_bounds__(64)
void scan2_k(const int* __restrict__ blksum3, int* __restrict__ blkoff3, int nb) {
    int p = blockIdx.x, lane = threadIdx.x;
    int v = (lane < nb) ? blksum3[p*64 + lane] : 0;
    int s = v;
    #pragma unroll
    for (int off = 1; off < 64; off <<= 1) {
        int t = __shfl_up(s, off);
        if (lane >= off) s += t;
    }
    if (lane < nb) blkoff3[p*64 + lane] = s - v;
}

__global__ __launch_bounds__(256)
void scan3_k(int* __restrict__ rowptr3, int* __restrict__ fillp3,
             const int* __restrict__ blkoff3, int n) {
    int p = blockIdx.y;
    int i = blockIdx.x * 256 + threadIdx.x;
    if (i < n) {
        int off = blkoff3[p*64 + (i >> 10)];
        rowptr3[p*(n+1) + i] += off;
        fillp3[p*n + i]      += off;
    }
    if (i == 0) rowptr3[p*(n+1) + n] = ET;
}

__global__ __launch_bounds__(256)
void fill3_k(const int* __restrict__ edges, int* __restrict__ fillp3,
             unsigned short* __restrict__ srcs3) {
    int e = blockIdx.x*256 + threadIdx.x;
    if (e >= 3*ET) return;
    int p = e / ET, i = e - p * ET;
    const int* src = edges + (size_t)p * 2 * N_EDG;
    const int* dst = src + N_EDG;
    int s, d;
    if (i < N_EDG) { s = src[i]; d = dst[i]; } else { s = i - N_EDG; d = s; }
    s = min(max(s, 0), N_NODES - 1);
    d = min(max(d, 0), N_NODES - 1);
    int pos = atomicAdd(&fillp3[p * N_NODES + d], 1);
    pos = min(max(pos, 0), ET - 1);
    srcs3[(size_t)p * ET + pos] = (unsigned short)s;
}

// ---------------- segment-softmax aggregation, 3 paths batched -----------
__global__ __launch_bounds__(256)
void agg3_k(const int* __restrict__ rowptr3, const unsigned short* __restrict__ srcs3,
            const float* __restrict__ ssrc3, const float* __restrict__ sdst3,
            const __half* __restrict__ hp3, const float* __restrict__ gatB, int l,
            unsigned short* __restrict__ outhi, unsigned short* __restrict__ outlo) {
    const int p = blockIdx.y;
    int wid  = (blockIdx.x * blockDim.x + threadIdx.x) >> 6;
    int lane = threadIdx.x & 63;
    if (wid >= N_NODES) return;
    const int n = wid;
    const int* rowptr = rowptr3 + p * (N_NODES + 1);
    const unsigned short* srcs = srcs3 + (size_t)p * ET;
    const float* s_src = ssrc3 + p * N_NODES * NH;
    const float* s_dst = sdst3 + p * N_NODES * NH;
    const __half* hp = hp3 + (size_t)p * N_NODES * HID;
    const float* bias = gatB + (2*p + l) * HID;
    int r0 = rowptr[n], r1 = rowptr[n + 1];
    r0 = min(max(r0, 0), ET); r1 = min(max(r1, r0), ET);

    // pass 1: denominator. lane = slot*8 + h1
    const int h1 = lane & 7, slot = lane >> 3;
    const float sd1 = s_dst[n*NH + h1];
    float dn = 0.f;
    for (int i = r0 + slot; i < r1; i += 8) {
        int s = srcs[i];
        float ev = s_src[s*NH + h1] + sd1;
        ev = ev > 0.f ? ev : 0.2f * ev;
        dn += __expf(ev);
    }
    dn += __shfl_xor(dn, 8);
    dn += __shfl_xor(dn, 16);
    dn += __shfl_xor(dn, 32);

    // pass 2: lane = eo*32 + sub; 16 B hp load per lane per edge
    const int sub = lane & 31, eo = lane >> 5;
    const int h2  = sub >> 2;
    const float rdn = 1.f / __shfl(dn, h2);
    const float sd2 = __shfl(sd1, h2);
    float a0=0.f,a1=0.f,a2=0.f,a3=0.f,a4=0.f,a5=0.f,a6=0.f,a7=0.f;
    for (int i = r0 + eo; i < r1; i += 2) {
        int s = srcs[i];
        float ev = s_src[s*NH + h2] + sd2;
        ev = ev > 0.f ? ev : 0.2f * ev;
        float ww = __expf(ev) * rdn;
        const __half2* hv = (const __half2*)(hp + (size_t)s * HID + sub * 8);
        __half2 p0 = hv[0], p1 = hv[1], p2 = hv[2], p3 = hv[3];
        float2 f0 = __half22float2(p0), f1 = __half22float2(p1);
        float2 f2 = __half22float2(p2), f3 = __half22float2(p3);
        a0 += ww*f0.x; a1 += ww*f0.y; a2 += ww*f1.x; a3 += ww*f1.y;
        a4 += ww*f2.x; a5 += ww*f2.y; a6 += ww*f3.x; a7 += ww*f3.y;
    }
    a0 += __shfl_xor(a0, 32); a1 += __shfl_xor(a1, 32);
    a2 += __shfl_xor(a2, 32); a3 += __shfl_xor(a3, 32);
    a4 += __shfl_xor(a4, 32); a5 += __shfl_xor(a5, 32);
    a6 += __shfl_xor(a6, 32); a7 += __shfl_xor(a7, 32);
    if (lane < 32) {
        float v[8] = {a0,a1,a2,a3,a4,a5,a6,a7};
        const float4 b0 = *(const float4*)&bias[sub*8];
        const float4 b1 = *(const float4*)&bias[sub*8 + 4];
        v[0]+=b0.x; v[1]+=b0.y; v[2]+=b0.z; v[3]+=b0.w;
        v[4]+=b1.x; v[5]+=b1.y; v[6]+=b1.z; v[7]+=b1.w;
        unsigned short hh[8], ll[8];
        #pragma unroll
        for (int k = 0; k < 8; ++k) {
            float e = v[k] > 0.f ? v[k] : expm1f(v[k]);   // ELU
            hh[k] = f2bf(e); ll[k] = f2bf(e - bf2f(hh[k]));
        }
        size_t o = (size_t)n * 768 + p * HID + sub * 8;
        *(uint4*)&outhi[o] = make_uint4(hh[0]|((unsigned)hh[1]<<16), hh[2]|((unsigned)hh[3]<<16),
                                        hh[4]|((unsigned)hh[5]<<16), hh[6]|((unsigned)hh[7]<<16));
        *(uint4*)&outlo[o] = make_uint4(ll[0]|((unsigned)ll[1]<<16), ll[2]|((unsigned)ll[3]<<16),
                                        ll[4]|((unsigned)ll[5]<<16), ll[6]|((unsigned)ll[7]<<16));
    }
}

// ---------------- semantic attention: scores -> softmax -> z -------------
__global__ __launch_bounds__(256)
void score_z_k(const float* t, const float* __restrict__ W2,
               const unsigned short* __restrict__ ehi,
               const unsigned short* __restrict__ elo,
               float* z) {
    int wid  = (blockIdx.x * blockDim.x + threadIdx.x) >> 6;
    int lane = threadIdx.x & 63;
    if (wid >= N_NODES) return;
    const int n = wid;
    float sc[3];
    #pragma unroll
    for (int p = 0; p < 3; ++p) {
        const float* tr = t + (size_t)(n*3 + p) * 128;
        float part = tr[lane] * W2[lane] + tr[64 + lane] * W2[64 + lane];
        #pragma unroll
        for (int o = 1; o < 64; o <<= 1) part += __shfl_xor(part, o);
        sc[p] = part;
    }
    float m  = fmaxf(sc[0], fmaxf(sc[1], sc[2]));
    float e0 = __expf(sc[0]-m), e1 = __expf(sc[1]-m), e2 = __expf(sc[2]-m);
    float rs = 1.f / (e0 + e1 + e2);
    e0 *= rs; e1 *= rs; e2 *= rs;
    const unsigned short* rh = ehi + (size_t)n * 768;
    const unsigned short* rl = elo + (size_t)n * 768;
    for (int c = lane; c < 256; c += 64) {
        float v0 = bf2f(rh[c])       + bf2f(rl[c]);
        float v1 = bf2f(rh[256 + c]) + bf2f(rl[256 + c]);
        float v2 = bf2f(rh[512 + c]) + bf2f(rl[512 + c]);
        z[(size_t)n*384 + c] = e0*v0 + e1*v1 + e2*v2;   // own row of t-arena
    }
}

__global__ __launch_bounds__(256)
void logits_k(const float* __restrict__ hcls, const float* __restrict__ W2,
              const float* __restrict__ b2, float* __restrict__ out) {
    int gid = blockIdx.x*256 + threadIdx.x;
    if (gid >= N_NODES * 2) return;
    int n = gid >> 1, o = gid & 1;
    const float* hr = hcls + (size_t)n * 128;
    float a = b2[o];
    #pragma unroll 4
    for (int j = 0; j < 128; ++j) a += hr[j] * W2[j*2 + o];
    out[gid] = a;
}

// -------------------------------------------------------------------------
extern "C" void kernel_launch(void* const* d_in, const int* in_sizes, int n_in,
                              void* d_out, int out_size, void* d_ws, size_t ws_size,
                              hipStream_t stream) {
    (void)in_sizes; (void)n_in; (void)out_size; (void)ws_size;
    const float* x     = (const float*)d_in[0];
    const int*   edges = (const int*)  d_in[1];
    const float* projW = (const float*)d_in[2];
    const float* projb = (const float*)d_in[3];
    const float* gatW  = (const float*)d_in[4];
    const float* gatAs = (const float*)d_in[5];
    const float* gatAd = (const float*)d_in[6];
    const float* gatB  = (const float*)d_in[7];
    const float* semW1 = (const float*)d_in[8];
    const float* semb1 = (const float*)d_in[9];
    const float* semW2 = (const float*)d_in[10];
    const float* clsW1 = (const float*)d_in[11];
    const float* clsb1 = (const float*)d_in[12];
    const float* clsW2 = (const float*)d_in[13];
    const float* clsb2 = (const float*)d_in[14];
    float* out = (float*)d_out;

    // ---- arena, high-water ~248 MB ----
    // [0,3P): hp3 (fp16 [3][N,256]); later tbuf [N,3,128] f32
    // [3P,9P): ehi [3P,6P) + elo [6P,9P); h0 pair overlays [3P,5P)
    //          (h0 dead before agg3_l0 writes e); later hcls at [3P,...)
    // [9P,...): scores, CSR, WT, srcs3 (ushort)
    char* base = (char*)d_ws;
    const size_t PLANE = (size_t)N_NODES * HID * 2;      // 25.6 MB
    __half*         hp3  = (__half*)(base);
    unsigned short* ehi  = (unsigned short*)(base + 3*PLANE);
    unsigned short* elo  = (unsigned short*)(base + 6*PLANE);
    unsigned short* h0hi = (unsigned short*)(base + 3*PLANE);
    unsigned short* h0lo = (unsigned short*)(base + 4*PLANE);
    char* small = base + 9*PLANE;
    float* ssrc3 = (float*)small;                          // 3*N*8 f32
    float* sdst3 = ssrc3 + 3*(size_t)N_NODES*NH;
    int*   rowptr3 = (int*)(sdst3 + 3*(size_t)N_NODES*NH); // 3*(N+1)
    int*   fillp3  = rowptr3 + 3*(N_NODES + 1);            // 3*N
    int*   blksum3 = fillp3 + 3*N_NODES;
    int*   blkoff3 = blksum3 + 192;
    unsigned short* WT = (unsigned short*)(blkoff3 + 192); // 9*131072 shorts
    unsigned short* srcs3 = WT + 9*131072;                 // 3*ET ushort
    // final-stage overlays:
    float* tbuf = (float*)base;                  // [N,3,128] f32
    float* hcls = (float*)(base + 3*PLANE);      // [N,128] f32

    dim3 blk(256);
    const int gx = (N_NODES + 127) / 128;     // 391
    const int NB = (N_NODES + 1023) / 1024;   // 49

    // weights + CSR
    cvtWall_k<<<dim3(256, 9), blk, 0, stream>>>(gatW, projW, semW1, clsW1, WT);
    zero_k  <<<(3*N_NODES+255)/256, blk, 0, stream>>>(fillp3, 3*N_NODES);
    count3_k<<<(3*ET+255)/256,      blk, 0, stream>>>(edges, fillp3);
    scan1_k <<<dim3(NB,3), 1024, 0, stream>>>(fillp3, rowptr3, blksum3, N_NODES);
    scan2_k <<<3, 64, 0, stream>>>(blksum3, blkoff3, NB);
    scan3_k <<<dim3((N_NODES+255)/256,3), blk, 0, stream>>>(rowptr3, fillp3, blkoff3, N_NODES);
    fill3_k <<<(3*ET+255)/256,      blk, 0, stream>>>(edges, fillp3, srcs3);

    // projection: h0pair = split(x @ projW + projb)
    mfma_gemm_k<256,0,1,1><<<dim3(gx,2), blk, 0, stream>>>(
        x, nullptr, nullptr, 128, WT + 6*131072, WT + 6*131072 + 65536, projb,
        nullptr, h0hi, h0lo, 256, N_NODES, 128);

    // GAT layers: all 3 meta-paths per dispatch
    for (int l = 0; l < 2; ++l) {
        if (l == 0)
            mfma_gemm3_k<<<dim3(gx,2,3), blk, 0, stream>>>(
                h0hi, h0lo, 0, HID, WT, 0, hp3, N_NODES);
        else
            mfma_gemm3_k<<<dim3(gx,2,3), blk, 0, stream>>>(
                ehi, elo, HID, 3*HID, WT, 1, hp3, N_NODES);
        attn_scores3_k<<<dim3((N_NODES*NH+255)/256, 3), blk, 0, stream>>>(
            hp3, gatAs, gatAd, l, ssrc3, sdst3);
        agg3_k<<<dim3((N_NODES*64)/256, 3), blk, 0, stream>>>(
            rowptr3, srcs3, ssrc3, sdst3, hp3, gatB, l, ehi, elo);
    }

    // semantic attention + classifier
    mfma_gemm_k<128,1,0,0><<<dim3((150000+127)/128, 1), blk, 0, stream>>>(
        nullptr, ehi, elo, 256, WT + 7*131072, WT + 7*131072 + 65536, semb1,
        tbuf, nullptr, nullptr, 128, 150000, 256);
    score_z_k<<<(N_NODES*64)/256, blk, 0, stream>>>(tbuf, semW2, ehi, elo, tbuf);
    mfma_gemm_k<128,2,0,1><<<dim3(gx, 1), blk, 0, stream>>>(
        tbuf, nullptr, nullptr, 384, WT + 8*131072, WT + 8*131072 + 65536, clsb1,
        hcls, nullptr, nullptr, 128, N_NODES, 256);
    logits_k<<<(N_NODES*2+255)/256, blk, 0, stream>>>(hcls, clsW2, clsb2, out);
}